// Round 4
// baseline (2942.967 us; speedup 1.0000x reference)
//
#include <hip/hip_runtime.h>
#include <hip/hip_cooperative_groups.h>
#include <math.h>

namespace cg = cooperative_groups;

#define LN2PI 1.83787706640934548356f

constexpr int GBLK = 512;            // blocks: 2/CU needed, <=128 VGPR gives 4/CU capacity (2x margin)
constexpr int BLK  = 256;            // threads per block
constexpr int GSZ  = GBLK * BLK;     // 131072 threads
constexpr int NWAVE = GSZ / 64;      // 2048 waves

// ---------------------------------------------------------------------------
// 4x4 matmul V = W @ M (row-major, m = r*4+c)
// ---------------------------------------------------------------------------
__device__ __forceinline__ void compute_V(const float* __restrict__ Wm,
                                          const float* __restrict__ Mm,
                                          float* V) {
    float w[16], m[16];
    #pragma unroll
    for (int k = 0; k < 16; ++k) { w[k] = Wm[k]; m[k] = Mm[k]; }
    #pragma unroll
    for (int r = 0; r < 4; ++r) {
        #pragma unroll
        for (int cc = 0; cc < 4; ++cc) {
            float s = w[r*4+0] * m[0*4+cc];
            s = fmaf(w[r*4+1], m[1*4+cc], s);
            s = fmaf(w[r*4+2], m[2*4+cc], s);
            s = fmaf(w[r*4+3], m[3*4+cc], s);
            V[r*4+cc] = s;
        }
    }
}

// ---------------------------------------------------------------------------
// phase: stem conv 5x5 s2 + relu
// ---------------------------------------------------------------------------
__device__ void phase_stem(int gtid, const float* __restrict__ x,
                           const float* __restrict__ w, const float* __restrict__ bias,
                           float* __restrict__ fea) {
    for (int idx = gtid; idx < 16*32*196; idx += GSZ) {
        int ox = idx % 14, oy = (idx/14) % 14, oc = (idx/196) % 32, b = idx/(196*32);
        float s = bias[oc];
        const float* xb = x + b*2*1024;
        const float* wc = w + oc*2*25;
        #pragma unroll
        for (int ic = 0; ic < 2; ++ic)
            #pragma unroll
            for (int ky = 0; ky < 5; ++ky)
                #pragma unroll
                for (int kx = 0; kx < 5; ++kx)
                    s = fmaf(xb[ic*1024 + (oy*2+ky)*32 + (ox*2+kx)],
                             wc[ic*25 + ky*5 + kx], s);
        fea[idx] = fmaxf(s, 0.f);
    }
}

// ---------------------------------------------------------------------------
// phase: primary caps
// ---------------------------------------------------------------------------
__device__ void phase_primary(int gtid, const float* __restrict__ fea,
                              const float* __restrict__ pw, const float* __restrict__ pb,
                              const float* __restrict__ aw, const float* __restrict__ ab,
                              float* __restrict__ M, float* __restrict__ a) {
    for (int idx = gtid; idx < 16*544*196; idx += GSZ) {
        int hw = idx % 196, o = (idx/196) % 544, b = idx/(196*544);
        const float* f = fea + b*32*196 + hw;
        if (o < 512) {
            float s = pb[o];
            #pragma unroll
            for (int c = 0; c < 32; ++c) s = fmaf(f[c*196], pw[o*32+c], s);
            M[(b*512+o)*196 + hw] = s;
        } else {
            int oo = o - 512;
            float s = ab[oo];
            #pragma unroll
            for (int c = 0; c < 32; ++c) s = fmaf(f[c*196], aw[oo*32+c], s);
            a[(b*32+oo)*196 + hw] = 1.f/(1.f + expf(-s));
        }
    }
}

// ---------------------------------------------------------------------------
// phase: patch extraction (p-major) + W transpose
// ---------------------------------------------------------------------------
__device__ void phase_patch(int gtid, const float* __restrict__ a_in,
                            const float* __restrict__ M_in,
                            float* __restrict__ aP, float* __restrict__ Mp,
                            int B, int K, int stride, int h, int w, int oh, int ow) {
    int P = oh*ow, KK = K*K, ni = B*KK;
    for (int idx = gtid; idx < 16*ni*P; idx += GSZ) {
        int i = idx % ni, p = (idx/ni) % P, b = idx/(ni*P);
        int Bi = i / KK, kk = i % KK, ki = kk / K, kj = kk % K;
        int py = p / ow, px = p % ow;
        int src = (py*stride + ki)*w + (px*stride + kj);
        int hw = h*w;
        aP[idx] = a_in[(b*B + Bi)*hw + src];
        const float* Ms = M_in + (size_t)((b*B + Bi)*16)*hw + src;
        float* Md = Mp + (size_t)idx*16;
        #pragma unroll
        for (int m = 0; m < 16; ++m) Md[m] = Ms[m*hw];
    }
}

__device__ void phase_wt(int gtid, const float* __restrict__ W, float* __restrict__ Wt,
                         int NI, int C) {
    for (int idx = gtid; idx < NI*C*16; idx += GSZ) {
        int m = idx % 16, i = (idx/16) % NI, c = idx/(16*NI);
        Wt[idx] = W[(i*C + c)*16 + m];
    }
}

// layer-4 patch: Mp4[(b*512+i)*16+m] with the faithful channel scramble
__device__ void phase_patch4(int gtid, const float* __restrict__ M3,
                             float* __restrict__ Mp) {
    for (int idx = gtid; idx < 16*512*16; idx += GSZ) {
        int m = idx & 15, i = (idx >> 4) & 511, b = idx >> 13;
        Mp[idx] = M3[b*8192 + (i >> 4)*256 + m*16 + (i & 15)];
    }
}

// ---------------------------------------------------------------------------
// phase S: EM stats, one wave per (b,j). Single pass, E[x^2] variance,
// R recomputed on the fly from (mxs,ism) + previous stats of this j.
// ---------------------------------------------------------------------------
template<int NI, int NJ, int P, int C, int KK, int SHARE, int COORD>
__device__ void phase_S(int wid, int lane, int t, float lam,
    const float* __restrict__ aP, const float* __restrict__ Mp,
    const float* __restrict__ Wt, const float* __restrict__ Wsh,
    const float* __restrict__ mxs, const float* __restrict__ ism,
    const float* __restrict__ ba, const float* __restrict__ bu,
    float* miu, float* isg, float* lss, float* aout,
    float* a_fin, float* M_fin, int fin)
{
    constexpr int NIT = (NI + 63) / 64;
    for (int job = wid; job < 16*NJ; job += NWAVE) {
        int j = job % NJ, bb = job / NJ;
        int c = j / P, p = j % P;
        const float* muO = miu + (size_t)(bb*NJ + j)*16;
        const float* isO = isg + (size_t)(bb*NJ + j)*16;
        float lssO = 0.f, aoO = 0.f;
        if (t > 0) { lssO = lss[bb*NJ + j]; aoO = aout[bb*NJ + j]; }
        const float* aPb = aP + (size_t)(bb*P + p)*NI;
        const float* Mpb = Mp + (size_t)(bb*P + p)*NI*16;
        const float* mxb = mxs + bb*NI;
        const float* imb = ism + bb*NI;

        float accw = 0.f, accm[16], acc2[16];
        #pragma unroll
        for (int m = 0; m < 16; ++m) { accm[m] = 0.f; acc2[m] = 0.f; }

        for (int it = 0; it < NIT; ++it) {
            int i = lane + it*64;
            if ((NI % 64 == 0) || (i < NI)) {
                const float* Wrow = SHARE ? (Wsh + ((i/KK)*C + c)*16)
                                          : (Wt + ((size_t)c*NI + i)*16);
                float V[16];
                compute_V(Wrow, Mpb + (size_t)i*16, V);
                if (COORD) {
                    int kk = i % KK;
                    V[0] += (float)(kk >> 2) * 0.25f;
                    V[1] += (float)(kk & 3) * 0.25f;
                }
                float r;
                if (t == 0) {
                    r = 1.f / NJ;
                } else {
                    float q = 0.f;
                    #pragma unroll
                    for (int m = 0; m < 16; ++m) {
                        float d = V[m] - muO[m];
                        q = fmaf(d*d, isO[m], q);
                    }
                    float logp = -0.5f * (16.f*LN2PI + lssO + q);
                    r = expf(aoO*logp - mxb[i]) * imb[i];
                }
                float wgt = r * aPb[i];
                accw += wgt;
                #pragma unroll
                for (int m = 0; m < 16; ++m) {
                    float t1 = wgt * V[m];
                    accm[m] += t1;
                    acc2[m] = fmaf(t1, V[m], acc2[m]);
                }
            }
        }

        for (int off = 1; off < 64; off <<= 1) {
            accw += __shfl_xor(accw, off);
            #pragma unroll
            for (int m = 0; m < 16; ++m) accm[m] += __shfl_xor(accm[m], off);
            #pragma unroll
            for (int m = 0; m < 16; ++m) acc2[m] += __shfl_xor(acc2[m], off);
        }

        float coeff = fmaxf(accw, 1e-8f);
        float lsum = 0.f, mu[16], isv[16];
        #pragma unroll
        for (int m = 0; m < 16; ++m) {
            mu[m] = accm[m] / coeff;
            float s = fmaxf(acc2[m]/coeff - mu[m]*mu[m], 1e-8f);
            lsum += logf(s);
            isv[m] = 1.f / s;
        }
        float ao = 1.f/(1.f + expf(-(lam * (ba[j % C] - (16.f*bu[j % C] + 0.5f*lsum) * coeff))));

        if (lane == 0) {
            float* mo = miu + (size_t)(bb*NJ + j)*16;
            float* io = isg + (size_t)(bb*NJ + j)*16;
            #pragma unroll
            for (int m = 0; m < 16; ++m) { mo[m] = mu[m]; io[m] = isv[m]; }
            lss[bb*NJ + j] = lsum;
            aout[bb*NJ + j] = ao;
            if (fin) {
                a_fin[bb*NJ + j] = ao;
                if (M_fin) {
                    #pragma unroll
                    for (int m = 0; m < 16; ++m)
                        M_fin[(size_t)(bb*16 + m)*NJ + j] = mu[m];  // faithful scramble
                }
            }
        }
    }
}

// ---------------------------------------------------------------------------
// phase R (wave per (b,i)): LSE over all NJ -> mxs, ism
// ---------------------------------------------------------------------------
template<int NI, int NJ, int P, int C>
__device__ void phase_Rw(int wid, int lane,
    const float* __restrict__ Mp, const float* __restrict__ W,
    const float* miu, const float* isg, const float* lss, const float* aout,
    float* mxs, float* ism)
{
    constexpr int NJL = (NJ + 63) / 64;
    for (int job = wid; job < 16*NI; job += NWAVE) {
        int i = job % NI, bb = job / NI;
        const float* Wi  = W + (size_t)i*C*16;
        const float* Mpb = Mp + ((size_t)(bb*P)*NI + i)*16;
        float mx = -3.0e38f, sm = 0.f;
        for (int k = 0; k < NJL; ++k) {
            int j = lane + k*64;
            if ((NJ % 64 == 0) || (j < NJ)) {
                int cc = j / P, p = j % P;
                float V[16];
                compute_V(Wi + cc*16, Mpb + (size_t)p*NI*16, V);
                const float* mo = miu + (size_t)(bb*NJ + j)*16;
                const float* io = isg + (size_t)(bb*NJ + j)*16;
                float q = 0.f;
                #pragma unroll
                for (int m = 0; m < 16; ++m) {
                    float d = V[m] - mo[m];
                    q = fmaf(d*d, io[m], q);
                }
                float logp = -0.5f * (16.f*LN2PI + lss[bb*NJ + j] + q);
                float sv = aout[bb*NJ + j] * logp;
                if (sv > mx) { sm = sm*expf(mx - sv) + 1.f; mx = sv; }
                else         { sm += expf(sv - mx); }
            }
        }
        for (int off = 1; off < 64; off <<= 1) {
            float mo_ = __shfl_xor(mx, off);
            float so_ = __shfl_xor(sm, off);
            float Mx = fmaxf(mx, mo_);
            sm = sm*expf(mx - Mx) + so_*expf(mo_ - Mx);
            mx = Mx;
        }
        if (lane == 0) { mxs[bb*NI + i] = mx; ism[bb*NI + i] = 1.f / sm; }
    }
}

// layer-4 R phase: one lane per (b,i), NJ=5 serial
__device__ void phase_R4(int gtid, const float* __restrict__ Mp4,
    const float* __restrict__ W4,
    const float* miu, const float* isg, const float* lss, const float* aout,
    float* mxs, float* ism)
{
    for (int idx = gtid; idx < 16*512; idx += GSZ) {
        int i = idx & 511, bb = idx >> 9;
        const float* Mm = Mp4 + (size_t)idx*16;
        float sv[5], mx = -3.0e38f;
        #pragma unroll
        for (int j = 0; j < 5; ++j) {
            float V[16];
            compute_V(W4 + ((i >> 4)*5 + j)*16, Mm, V);
            V[0] += (float)((i & 15) >> 2) * 0.25f;
            V[1] += (float)(i & 3) * 0.25f;
            const float* mo = miu + (bb*5 + j)*16;
            const float* io = isg + (bb*5 + j)*16;
            float q = 0.f;
            #pragma unroll
            for (int m = 0; m < 16; ++m) {
                float d = V[m] - mo[m];
                q = fmaf(d*d, io[m], q);
            }
            float logp = -0.5f * (16.f*LN2PI + lss[bb*5 + j] + q);
            sv[j] = aout[bb*5 + j] * logp;
            mx = fmaxf(mx, sv[j]);
        }
        float sum = 0.f;
        #pragma unroll
        for (int j = 0; j < 5; ++j) sum += expf(sv[j] - mx);
        mxs[idx] = mx;
        ism[idx] = 1.f / sum;
    }
}

// ---------------------------------------------------------------------------
// the whole network as one cooperative kernel
// ---------------------------------------------------------------------------
struct KArgs {
    const float *x, *conv_w, *conv_b, *pose_w, *pose_b, *act_w, *act_b;
    const float *W2, *ba2, *bu2, *W3, *ba3, *bu3, *W4, *ba4, *bu4;
    float *fea, *a1, *M1, *aP, *Mp, *Wt;
    float *miu, *isg, *lss, *ao, *mxs, *ism;
    float *a2, *M2, *a3, *M3, *out;
};

__global__ __launch_bounds__(BLK, 4) void k_capsnet(KArgs A) {
    cg::grid_group grid = cg::this_grid();
    int gtid = blockIdx.x * BLK + threadIdx.x;
    int lane = threadIdx.x & 63;
    int wid  = gtid >> 6;
    const float lams[3] = {5.0e-4f, 9.75e-4f, 1.42625e-3f};

    phase_stem(gtid, A.x, A.conv_w, A.conv_b, A.fea);
    __threadfence(); grid.sync();
    phase_primary(gtid, A.fea, A.pose_w, A.pose_b, A.act_w, A.act_b, A.M1, A.a1);
    __threadfence(); grid.sync();

    // ---- layer 2: NI=288, NJ=1152, P=36, C=32 ----
    phase_patch(gtid, A.a1, A.M1, A.aP, A.Mp, 32, 3, 2, 14, 14, 6, 6);
    phase_wt(gtid, A.W2, A.Wt, 288, 32);
    __threadfence(); grid.sync();
    for (int t = 0; t < 3; ++t) {
        phase_S<288,1152,36,32,9,0,0>(wid, lane, t, lams[t], A.aP, A.Mp, A.Wt, A.W2,
            A.mxs, A.ism, A.ba2, A.bu2, A.miu, A.isg, A.lss, A.ao, A.a2, A.M2, t == 2);
        __threadfence(); grid.sync();
        if (t < 2) {
            phase_Rw<288,1152,36,32>(wid, lane, A.Mp, A.W2, A.miu, A.isg, A.lss, A.ao,
                                     A.mxs, A.ism);
            __threadfence(); grid.sync();
        }
    }

    // ---- layer 3: NI=288, NJ=512, P=16, C=32 ----
    phase_patch(gtid, A.a2, A.M2, A.aP, A.Mp, 32, 3, 1, 6, 6, 4, 4);
    phase_wt(gtid, A.W3, A.Wt, 288, 32);
    __threadfence(); grid.sync();
    for (int t = 0; t < 3; ++t) {
        phase_S<288,512,16,32,9,0,0>(wid, lane, t, lams[t], A.aP, A.Mp, A.Wt, A.W3,
            A.mxs, A.ism, A.ba3, A.bu3, A.miu, A.isg, A.lss, A.ao, A.a3, A.M3, t == 2);
        __threadfence(); grid.sync();
        if (t < 2) {
            phase_Rw<288,512,16,32>(wid, lane, A.Mp, A.W3, A.miu, A.isg, A.lss, A.ao,
                                    A.mxs, A.ism);
            __threadfence(); grid.sync();
        }
    }

    // ---- layer 4: NI=512, NJ=5, P=1, C=5, share+coord ----
    phase_patch4(gtid, A.M3, A.Mp);
    __threadfence(); grid.sync();
    for (int t = 0; t < 3; ++t) {
        phase_S<512,5,1,5,16,1,1>(wid, lane, t, lams[t], A.a3, A.Mp, nullptr, A.W4,
            A.mxs, A.ism, A.ba4, A.bu4, A.miu, A.isg, A.lss, A.ao, A.out, nullptr, t == 2);
        if (t < 2) {
            __threadfence(); grid.sync();
            phase_R4(gtid, A.Mp, A.W4, A.miu, A.isg, A.lss, A.ao, A.mxs, A.ism);
            __threadfence(); grid.sync();
        }
    }
}

// ---------------------------------------------------------------------------
// host
// ---------------------------------------------------------------------------
extern "C" void kernel_launch(void* const* d_in, const int* in_sizes, int n_in,
                              void* d_out, int out_size, void* d_ws, size_t ws_size,
                              hipStream_t stream) {
    (void)in_sizes; (void)n_in; (void)out_size; (void)ws_size;

    float* ws   = (float*)d_ws;
    float* fea  = ws;                    // 100352
    float* a1   = fea  + 100352;         // 100352
    float* M1   = a1   + 100352;         // 1605632
    float* aP   = M1   + 1605632;        // 165888 (max)
    float* Mp   = aP   + 165888;         // 2654208 (max)
    float* Wt   = Mp   + 2654208;        // 147456
    float* miu  = Wt   + 147456;         // 294912
    float* isg  = miu  + 294912;         // 294912
    float* lssb = isg  + 294912;         // 18432
    float* ao   = lssb + 18432;          // 18432
    float* mxs  = ao   + 18432;          // 8192
    float* ismb = mxs  + 8192;           // 8192
    float* a2   = ismb + 8192;           // 18432
    float* M2   = a2   + 18432;          // 294912
    float* a3   = M2   + 294912;         // 8192
    float* M3   = a3   + 8192;           // 131072

    KArgs A;
    A.x      = (const float*)d_in[0];
    A.conv_w = (const float*)d_in[1];
    A.conv_b = (const float*)d_in[2];
    A.pose_w = (const float*)d_in[3];
    A.pose_b = (const float*)d_in[4];
    A.act_w  = (const float*)d_in[5];
    A.act_b  = (const float*)d_in[6];
    A.W2     = (const float*)d_in[7];
    A.ba2    = (const float*)d_in[8];
    A.bu2    = (const float*)d_in[9];
    A.W3     = (const float*)d_in[10];
    A.ba3    = (const float*)d_in[11];
    A.bu3    = (const float*)d_in[12];
    A.W4     = (const float*)d_in[13];
    A.ba4    = (const float*)d_in[14];
    A.bu4    = (const float*)d_in[15];
    A.fea = fea; A.a1 = a1; A.M1 = M1; A.aP = aP; A.Mp = Mp; A.Wt = Wt;
    A.miu = miu; A.isg = isg; A.lss = lssb; A.ao = ao; A.mxs = mxs; A.ism = ismb;
    A.a2 = a2; A.M2 = M2; A.a3 = a3; A.M3 = M3;
    A.out = (float*)d_out;

    void* params[] = { &A };
    hipLaunchCooperativeKernel((void*)k_capsnet, dim3(GBLK), dim3(BLK),
                               params, 0, stream);
}

// Round 5
// 755.486 us; speedup vs baseline: 3.8955x; 3.8955x over previous
//
#include <hip/hip_runtime.h>
#include <math.h>

#define LN2PI 1.83787706640934548356f

// ---------------------------------------------------------------------------
// stem: conv 5x5 stride 2 valid + bias + relu : (16,2,32,32) -> (16,32,14,14)
// ---------------------------------------------------------------------------
__global__ void k_stem(const float* __restrict__ x, const float* __restrict__ w,
                       const float* __restrict__ bias, float* __restrict__ fea) {
    int idx = blockIdx.x * blockDim.x + threadIdx.x;
    if (idx >= 16*32*14*14) return;
    int ox = idx % 14, oy = (idx/14) % 14, oc = (idx/196) % 32, b = idx/(196*32);
    float s = bias[oc];
    const float* xb = x + b*2*1024;
    const float* wc = w + oc*2*25;
    #pragma unroll
    for (int ic = 0; ic < 2; ++ic)
        #pragma unroll
        for (int ky = 0; ky < 5; ++ky)
            #pragma unroll
            for (int kx = 0; kx < 5; ++kx)
                s = fmaf(xb[ic*1024 + (oy*2+ky)*32 + (ox*2+kx)],
                         wc[ic*25 + ky*5 + kx], s);
    fea[idx] = fmaxf(s, 0.f);
}

// ---------------------------------------------------------------------------
// primary caps
// ---------------------------------------------------------------------------
__global__ void k_primary(const float* __restrict__ fea,
                          const float* __restrict__ pw, const float* __restrict__ pb,
                          const float* __restrict__ aw, const float* __restrict__ ab,
                          float* __restrict__ M, float* __restrict__ a) {
    int idx = blockIdx.x * blockDim.x + threadIdx.x;
    if (idx >= 16*544*196) return;
    int hw = idx % 196, o = (idx/196) % 544, b = idx/(196*544);
    const float* f = fea + b*32*196 + hw;
    if (o < 512) {
        float s = pb[o];
        #pragma unroll
        for (int c = 0; c < 32; ++c) s = fmaf(f[c*196], pw[o*32+c], s);
        M[(b*512+o)*196 + hw] = s;
    } else {
        int oo = o - 512;
        float s = ab[oo];
        #pragma unroll
        for (int c = 0; c < 32; ++c) s = fmaf(f[c*196], aw[oo*32+c], s);
        a[(b*32+oo)*196 + hw] = 1.f/(1.f + expf(-s));
    }
}

// ---------------------------------------------------------------------------
// patch extraction, p-major: aP[(b*P+p)*ni + i], Mp[((b*P+p)*ni + i)*16]
// ---------------------------------------------------------------------------
__global__ void k_patch(const float* __restrict__ a_in, const float* __restrict__ M_in,
                        float* __restrict__ aP, float* __restrict__ Mp,
                        int B, int K, int stride, int h, int w, int oh, int ow) {
    int P = oh*ow, KK = K*K, ni = B*KK;
    int idx = blockIdx.x * blockDim.x + threadIdx.x;
    if (idx >= 16*ni*P) return;
    int i = idx % ni, p = (idx/ni) % P, b = idx/(ni*P);
    int Bi = i / KK, kk = i % KK, ki = kk / K, kj = kk % K;
    int py = p / ow, px = p % ow;
    int src = (py*stride + ki)*w + (px*stride + kj);
    int hw = h*w;
    aP[idx] = a_in[(b*B + Bi)*hw + src];
    const float* Ms = M_in + (size_t)((b*B + Bi)*16)*hw + src;
    float* Md = Mp + (size_t)idx*16;
    #pragma unroll
    for (int m = 0; m < 16; ++m) Md[m] = Ms[m*hw];
}

// W transpose: Wt[(c*NI+i)*16+m] = W[(i*C+c)*16+m]
__global__ void k_wt(const float* __restrict__ W, float* __restrict__ Wt,
                     int NI, int C) {
    int idx = blockIdx.x * blockDim.x + threadIdx.x;
    if (idx >= NI*C*16) return;
    int m = idx % 16, i = (idx/16) % NI, c = idx/(16*NI);
    Wt[idx] = W[(i*C + c)*16 + m];
}

// ---------------------------------------------------------------------------
// EM stats: one wave per (b,j). Reads Rt[j][i] contiguously; one-pass E[x^2].
// Small live set; waves_per_eu(2,4) stops the spill-happy 8-wave heuristic.
// ---------------------------------------------------------------------------
template<int NI, int NJ, int P, int C>
__global__ __launch_bounds__(64) __attribute__((amdgpu_waves_per_eu(2,4)))
void k_stats(const float* __restrict__ aP, const float* __restrict__ Mp,
             const float* __restrict__ Wt, const float* __restrict__ Rt,
             const float* __restrict__ beta_a, const float* __restrict__ beta_u,
             float* __restrict__ muT, float* __restrict__ isT,
             float2* __restrict__ lsa,
             float* __restrict__ a_fin, float* __restrict__ M_fin,
             int t, float lam, int fin)
{
    constexpr int NIT = (NI + 63) / 64;
    constexpr int BNJ = 16*NJ;
    int g  = blockIdx.x % (16*P);
    int c  = blockIdx.x / (16*P);
    int bb = g / P, p = g % P;
    int j  = c*P + p;
    int lane = threadIdx.x;

    const float* aPb  = aP + (size_t)(bb*P + p)*NI;
    const float* Mpb  = Mp + (size_t)(bb*P + p)*NI*16;
    const float* Wtc  = Wt + (size_t)c*NI*16;
    const float* Rrow = Rt + (size_t)(bb*NJ + j)*NI;

    float accw = 0.f, accm[16], acc2[16];
    #pragma unroll
    for (int m = 0; m < 16; ++m) { accm[m] = 0.f; acc2[m] = 0.f; }

    for (int it = 0; it < NIT; ++it) {
        int i = lane + it*64;
        if ((NI % 64 == 0) || (i < NI)) {
            float r = (t == 0) ? (1.f/NJ) : Rrow[i];
            float wgt = r * aPb[i];
            const float4* Mr = (const float4*)(Mpb + (size_t)i*16);
            const float4* Wr = (const float4*)(Wtc + (size_t)i*16);
            float4 m0 = Mr[0], m1 = Mr[1], m2 = Mr[2], m3 = Mr[3];
            accw += wgt;
            #pragma unroll
            for (int rr = 0; rr < 4; ++rr) {
                float4 w = Wr[rr];
                float v0 = fmaf(w.w, m3.x, fmaf(w.z, m2.x, fmaf(w.y, m1.x, w.x*m0.x)));
                float v1 = fmaf(w.w, m3.y, fmaf(w.z, m2.y, fmaf(w.y, m1.y, w.x*m0.y)));
                float v2 = fmaf(w.w, m3.z, fmaf(w.z, m2.z, fmaf(w.y, m1.z, w.x*m0.z)));
                float v3 = fmaf(w.w, m3.w, fmaf(w.z, m2.w, fmaf(w.y, m1.w, w.x*m0.w)));
                float t0 = wgt*v0, t1 = wgt*v1, t2 = wgt*v2, t3 = wgt*v3;
                accm[rr*4+0] += t0; acc2[rr*4+0] = fmaf(t0, v0, acc2[rr*4+0]);
                accm[rr*4+1] += t1; acc2[rr*4+1] = fmaf(t1, v1, acc2[rr*4+1]);
                accm[rr*4+2] += t2; acc2[rr*4+2] = fmaf(t2, v2, acc2[rr*4+2]);
                accm[rr*4+3] += t3; acc2[rr*4+3] = fmaf(t3, v3, acc2[rr*4+3]);
            }
        }
    }

    for (int off = 1; off < 64; off <<= 1) {
        accw += __shfl_xor(accw, off);
        #pragma unroll
        for (int m = 0; m < 16; ++m) accm[m] += __shfl_xor(accm[m], off);
        #pragma unroll
        for (int m = 0; m < 16; ++m) acc2[m] += __shfl_xor(acc2[m], off);
    }

    float coeff = fmaxf(accw, 1e-8f);
    float lsum = 0.f, mu[16], isv[16];
    #pragma unroll
    for (int m = 0; m < 16; ++m) {
        mu[m] = accm[m] / coeff;
        float s = fmaxf(acc2[m]/coeff - mu[m]*mu[m], 1e-8f);
        lsum += logf(s);
        isv[m] = 1.f / s;
    }
    float ao = 1.f/(1.f + expf(-(lam * (beta_a[j % C] - (16.f*beta_u[j % C] + 0.5f*lsum) * coeff))));

    if (lane == 0) {
        #pragma unroll
        for (int m = 0; m < 16; ++m) {
            muT[m*BNJ + bb*NJ + j] = mu[m];
            isT[m*BNJ + bb*NJ + j] = isv[m];
        }
        lsa[bb*NJ + j] = make_float2(lsum, ao);
        if (fin) {
            a_fin[bb*NJ + j] = ao;
            #pragma unroll
            for (int m = 0; m < 16; ++m)
                M_fin[(size_t)(bb*16 + m)*NJ + j] = mu[m];   // faithful transpose scramble
        }
    }
}

// ---------------------------------------------------------------------------
// R update: one wave per (b,i). softmax over j -> writes Rt[j][i] (scattered
// dword writes into L2; reads of stats are coalesced via muT/isT/lsa).
// W row + M patch staged in LDS with stride-20 padding (b128-aligned, banks spread).
// ---------------------------------------------------------------------------
template<int NI, int NJ, int P, int C>
__global__ __launch_bounds__(64) __attribute__((amdgpu_waves_per_eu(2,4)))
void k_R(const float* __restrict__ Mp, const float* __restrict__ W,
         const float* __restrict__ muT, const float* __restrict__ isT,
         const float2* __restrict__ lsa, float* __restrict__ Rt)
{
    constexpr int NJL = (NJ + 63) / 64;
    constexpr int BNJ = 16*NJ;
    constexpr int WS = 20;
    __shared__ float Wl[C*WS];
    __shared__ float Ml[P*WS];
    int i = blockIdx.x % NI, bb = blockIdx.x / NI;
    int lane = threadIdx.x;

    const float* Wsrc = W + (size_t)i*C*16;
    for (int k = lane; k < C*16; k += 64) Wl[(k/16)*WS + (k%16)] = Wsrc[k];
    for (int k = lane; k < P*16; k += 64) {
        int p = k/16, m = k%16;
        Ml[p*WS + m] = Mp[((size_t)(bb*P + p)*NI + i)*16 + m];
    }
    __syncthreads();

    float sv[NJL];
    float mx = -3.0e38f;
    #pragma unroll
    for (int k = 0; k < NJL; ++k) {
        int j = lane + k*64;
        sv[k] = -3.0e38f;
        if ((NJ % 64 == 0) || (j < NJ)) {
            int c = j / P, p = j % P;
            const float4* Mr = (const float4*)(Ml + p*WS);
            const float4* Wr = (const float4*)(Wl + c*WS);
            float4 m0 = Mr[0], m1 = Mr[1], m2 = Mr[2], m3 = Mr[3];
            float q = 0.f;
            #pragma unroll
            for (int rr = 0; rr < 4; ++rr) {
                float4 w = Wr[rr];
                float v0 = fmaf(w.w, m3.x, fmaf(w.z, m2.x, fmaf(w.y, m1.x, w.x*m0.x)));
                float v1 = fmaf(w.w, m3.y, fmaf(w.z, m2.y, fmaf(w.y, m1.y, w.x*m0.y)));
                float v2 = fmaf(w.w, m3.z, fmaf(w.z, m2.z, fmaf(w.y, m1.z, w.x*m0.z)));
                float v3 = fmaf(w.w, m3.w, fmaf(w.z, m2.w, fmaf(w.y, m1.w, w.x*m0.w)));
                float d0 = v0 - muT[(rr*4+0)*BNJ + bb*NJ + j];
                float d1 = v1 - muT[(rr*4+1)*BNJ + bb*NJ + j];
                float d2 = v2 - muT[(rr*4+2)*BNJ + bb*NJ + j];
                float d3 = v3 - muT[(rr*4+3)*BNJ + bb*NJ + j];
                q = fmaf(d0*d0, isT[(rr*4+0)*BNJ + bb*NJ + j], q);
                q = fmaf(d1*d1, isT[(rr*4+1)*BNJ + bb*NJ + j], q);
                q = fmaf(d2*d2, isT[(rr*4+2)*BNJ + bb*NJ + j], q);
                q = fmaf(d3*d3, isT[(rr*4+3)*BNJ + bb*NJ + j], q);
            }
            float2 la = lsa[bb*NJ + j];
            float logp = -0.5f * (16.f*LN2PI + la.x + q);
            sv[k] = la.y * logp;
        }
        mx = fmaxf(mx, sv[k]);
    }
    for (int off = 1; off < 64; off <<= 1) mx = fmaxf(mx, __shfl_xor(mx, off));
    float sm = 0.f;
    #pragma unroll
    for (int k = 0; k < NJL; ++k) {
        int j = lane + k*64;
        if ((NJ % 64 == 0) || (j < NJ)) { sv[k] = expf(sv[k] - mx); sm += sv[k]; }
    }
    for (int off = 1; off < 64; off <<= 1) sm += __shfl_xor(sm, off);
    float inv = 1.f / sm;
    #pragma unroll
    for (int k = 0; k < NJL; ++k) {
        int j = lane + k*64;
        if ((NJ % 64 == 0) || (j < NJ))
            Rt[(size_t)(bb*NJ + j)*NI + i] = sv[k] * inv;
    }
}

// ---------------------------------------------------------------------------
// layer 4 fused (verified in round 2): patch + 3 EM iterations, block per batch.
// ---------------------------------------------------------------------------
__global__ __launch_bounds__(256) void k_layer4(
    const float* __restrict__ a3, const float* __restrict__ M3,
    const float* __restrict__ W4, const float* __restrict__ ba4,
    const float* __restrict__ bu4, float* __restrict__ out)
{
    __shared__ float sM[512*16];
    __shared__ float sA[512];
    __shared__ float sW[32*5*16];
    __shared__ float sR[512*5];
    __shared__ float red[4][17];
    __shared__ float sStat[5][34];

    int b = blockIdx.x, tid = threadIdx.x;
    int lane = tid & 63, wave = tid >> 6;

    for (int k = tid; k < 512*16; k += 256) {
        int i = k >> 4, m = k & 15;
        sM[k] = M3[b*8192 + (i & ~15)*16 + m*16 + (i & 15)];
    }
    for (int k = tid; k < 512; k += 256)  sA[k] = a3[b*512 + k];
    for (int k = tid; k < 2560; k += 256) sW[k] = W4[k];
    for (int k = tid; k < 2560; k += 256) sR[k] = 0.2f;
    __syncthreads();

    const float lams[3] = {5.0e-4f, 9.75e-4f, 1.426250e-3f};

    for (int t = 0; t < 3; ++t) {
        float lam = lams[t];
        for (int j = 0; j < 5; ++j) {
            float cw = 0.f, cm[16];
            float Vr[2][16], wr[2];
            #pragma unroll
            for (int m = 0; m < 16; ++m) cm[m] = 0.f;
            #pragma unroll
            for (int u = 0; u < 2; ++u) {
                int i = tid + u*256;
                float wgt = sR[i*5 + j] * sA[i];
                const float* Wm = &sW[((i>>4)*5 + j)*16];
                const float* Mm = &sM[i*16];
                float V[16];
                #pragma unroll
                for (int r = 0; r < 4; ++r)
                    #pragma unroll
                    for (int cc = 0; cc < 4; ++cc) {
                        float s = Wm[r*4+0]*Mm[0*4+cc];
                        s = fmaf(Wm[r*4+1], Mm[1*4+cc], s);
                        s = fmaf(Wm[r*4+2], Mm[2*4+cc], s);
                        s = fmaf(Wm[r*4+3], Mm[3*4+cc], s);
                        V[r*4+cc] = s;
                    }
                V[0] += (float)((i & 15) >> 2) * 0.25f;
                V[1] += (float)(i & 3) * 0.25f;
                wr[u] = wgt; cw += wgt;
                #pragma unroll
                for (int m = 0; m < 16; ++m) { Vr[u][m] = V[m]; cm[m] = fmaf(wgt, V[m], cm[m]); }
            }
            for (int off = 1; off < 64; off <<= 1) {
                cw += __shfl_xor(cw, off);
                #pragma unroll
                for (int m = 0; m < 16; ++m) cm[m] += __shfl_xor(cm[m], off);
            }
            if (lane == 0) { red[wave][0] = cw; for (int m = 0; m < 16; ++m) red[wave][1+m] = cm[m]; }
            __syncthreads();
            float coeff = fmaxf(red[0][0]+red[1][0]+red[2][0]+red[3][0], 1e-8f);
            float mu[16];
            #pragma unroll
            for (int m = 0; m < 16; ++m)
                mu[m] = (red[0][1+m]+red[1][1+m]+red[2][1+m]+red[3][1+m]) / coeff;
            __syncthreads();
            float cs[16];
            #pragma unroll
            for (int m = 0; m < 16; ++m) cs[m] = 0.f;
            #pragma unroll
            for (int u = 0; u < 2; ++u)
                #pragma unroll
                for (int m = 0; m < 16; ++m) {
                    float d = Vr[u][m] - mu[m];
                    cs[m] = fmaf(wr[u], d*d, cs[m]);
                }
            for (int off = 1; off < 64; off <<= 1) {
                #pragma unroll
                for (int m = 0; m < 16; ++m) cs[m] += __shfl_xor(cs[m], off);
            }
            if (lane == 0) for (int m = 0; m < 16; ++m) red[wave][m] = cs[m];
            __syncthreads();
            float lsum = 0.f, isv[16];
            #pragma unroll
            for (int m = 0; m < 16; ++m) {
                float s = fmaxf((red[0][m]+red[1][m]+red[2][m]+red[3][m]) / coeff, 1e-8f);
                lsum += logf(s);
                isv[m] = 1.f / s;
            }
            float ao = 1.f/(1.f + expf(-(lam * (ba4[j] - (16.f*bu4[j] + 0.5f*lsum) * coeff))));
            if (tid == 0) {
                for (int m = 0; m < 16; ++m) { sStat[j][m] = mu[m]; sStat[j][16+m] = isv[m]; }
                sStat[j][32] = lsum; sStat[j][33] = ao;
            }
            __syncthreads();
        }
        if (t < 2) {
            #pragma unroll
            for (int u = 0; u < 2; ++u) {
                int i = tid + u*256;
                const float* Mm = &sM[i*16];
                float sv[5], mxv = -3.0e38f;
                #pragma unroll
                for (int j = 0; j < 5; ++j) {
                    const float* Wm = &sW[((i>>4)*5 + j)*16];
                    float V[16];
                    #pragma unroll
                    for (int r = 0; r < 4; ++r)
                        #pragma unroll
                        for (int cc = 0; cc < 4; ++cc) {
                            float s = Wm[r*4+0]*Mm[0*4+cc];
                            s = fmaf(Wm[r*4+1], Mm[1*4+cc], s);
                            s = fmaf(Wm[r*4+2], Mm[2*4+cc], s);
                            s = fmaf(Wm[r*4+3], Mm[3*4+cc], s);
                            V[r*4+cc] = s;
                        }
                    V[0] += (float)((i & 15) >> 2) * 0.25f;
                    V[1] += (float)(i & 3) * 0.25f;
                    float q = 0.f;
                    #pragma unroll
                    for (int m = 0; m < 16; ++m) {
                        float d = V[m] - sStat[j][m];
                        q = fmaf(d*d, sStat[j][16+m], q);
                    }
                    float logp = -0.5f * (16.f*LN2PI + sStat[j][32] + q);
                    sv[j] = sStat[j][33] * logp;
                    mxv = fmaxf(mxv, sv[j]);
                }
                float sum = 0.f;
                #pragma unroll
                for (int j = 0; j < 5; ++j) { sv[j] = expf(sv[j] - mxv); sum += sv[j]; }
                float inv = 1.f / sum;
                #pragma unroll
                for (int j = 0; j < 5; ++j) sR[i*5 + j] = sv[j] * inv;
            }
            __syncthreads();
        }
    }
    if (tid < 5) out[b*5 + tid] = sStat[tid][33];
}

// ---------------------------------------------------------------------------
// host: one EM layer (layers 2/3)
// ---------------------------------------------------------------------------
template<int NI, int NJ, int P, int C>
static void run_em(hipStream_t stream,
                   const float* aP, const float* Mp, const float* W, const float* Wt,
                   const float* ba, const float* bu, float* Rt,
                   float* muT, float* isT, float2* lsa,
                   float* a_fin, float* M_fin)
{
    const float lams[3] = {5.0e-4f, 9.75e-4f, 1.426250e-3f};
    for (int t = 0; t < 3; ++t) {
        k_stats<NI,NJ,P,C><<<16*NJ, 64, 0, stream>>>(
            aP, Mp, Wt, Rt, ba, bu, muT, isT, lsa, a_fin, M_fin,
            t, lams[t], (t == 2) ? 1 : 0);
        if (t < 2) {
            k_R<NI,NJ,P,C><<<16*NI, 64, 0, stream>>>(
                Mp, W, muT, isT, lsa, Rt);
        }
    }
}

extern "C" void kernel_launch(void* const* d_in, const int* in_sizes, int n_in,
                              void* d_out, int out_size, void* d_ws, size_t ws_size,
                              hipStream_t stream) {
    (void)in_sizes; (void)n_in; (void)out_size; (void)ws_size;
    const float* x       = (const float*)d_in[0];
    const float* conv_w  = (const float*)d_in[1];
    const float* conv_b  = (const float*)d_in[2];
    const float* pose_w  = (const float*)d_in[3];
    const float* pose_b  = (const float*)d_in[4];
    const float* act_w   = (const float*)d_in[5];
    const float* act_b   = (const float*)d_in[6];
    const float* W2      = (const float*)d_in[7];
    const float* beta_a2 = (const float*)d_in[8];
    const float* beta_u2 = (const float*)d_in[9];
    const float* W3      = (const float*)d_in[10];
    const float* beta_a3 = (const float*)d_in[11];
    const float* beta_u3 = (const float*)d_in[12];
    const float* W4      = (const float*)d_in[13];
    const float* beta_a4 = (const float*)d_in[14];
    const float* beta_u4 = (const float*)d_in[15];

    // workspace layout (floats), ~44.6 MB total
    float* ws   = (float*)d_ws;
    float* fea  = ws;                    // 100352
    float* a1   = fea  + 100352;         // 100352
    float* M1   = a1   + 100352;         // 1605632
    float* aP   = M1   + 1605632;        // 165888 (max)
    float* Mp   = aP   + 165888;         // 2654208 (max)
    float* Wt   = Mp   + 2654208;        // 147456
    float* muT  = Wt   + 147456;         // 294912 (16 x 16*1152)
    float* isT  = muT  + 294912;         // 294912
    float* lsa  = isT  + 294912;         // 36864 (float2 x 18432)
    float* Rt   = lsa  + 36864;          // 5308416 (max 16*1152*288)
    float* a2   = Rt   + 5308416;        // 18432
    float* M2   = a2   + 18432;          // 294912
    float* a3   = M2   + 294912;         // 8192
    float* M3   = a3   + 8192;           // 131072

    // stem + primary caps
    k_stem<<<(16*32*196 + 255)/256, 256, 0, stream>>>(x, conv_w, conv_b, fea);
    k_primary<<<(16*544*196 + 255)/256, 256, 0, stream>>>(fea, pose_w, pose_b,
                                                          act_w, act_b, M1, a1);

    // layer 2: NI=288, NJ=1152, P=36, C=32
    k_patch<<<(16*288*36 + 255)/256, 256, 0, stream>>>(a1, M1, aP, Mp, 32, 3, 2, 14, 14, 6, 6);
    k_wt<<<(288*32*16 + 255)/256, 256, 0, stream>>>(W2, Wt, 288, 32);
    run_em<288,1152,36,32>(stream, aP, Mp, W2, Wt, beta_a2, beta_u2, Rt,
                           muT, isT, (float2*)lsa, a2, M2);

    // layer 3: NI=288, NJ=512, P=16, C=32
    k_patch<<<(16*288*16 + 255)/256, 256, 0, stream>>>(a2, M2, aP, Mp, 32, 3, 1, 6, 6, 4, 4);
    k_wt<<<(288*32*16 + 255)/256, 256, 0, stream>>>(W3, Wt, 288, 32);
    run_em<288,512,16,32>(stream, aP, Mp, W3, Wt, beta_a3, beta_u3, Rt,
                          muT, isT, (float2*)lsa, a3, M3);

    // layer 4 fused
    k_layer4<<<16, 256, 0, stream>>>(a3, M3, W4, beta_a4, beta_u4, (float*)d_out);
}

// Round 6
// 739.466 us; speedup vs baseline: 3.9799x; 1.0217x over previous
//
#include <hip/hip_runtime.h>
#include <math.h>

#define LN2PI 1.83787706640934548356f

// ---------------------------------------------------------------------------
// stem: conv 5x5 stride 2 valid + bias + relu : (16,2,32,32) -> (16,32,14,14)
// ---------------------------------------------------------------------------
__global__ void k_stem(const float* __restrict__ x, const float* __restrict__ w,
                       const float* __restrict__ bias, float* __restrict__ fea) {
    int idx = blockIdx.x * blockDim.x + threadIdx.x;
    if (idx >= 16*32*14*14) return;
    int ox = idx % 14, oy = (idx/14) % 14, oc = (idx/196) % 32, b = idx/(196*32);
    float s = bias[oc];
    const float* xb = x + b*2*1024;
    const float* wc = w + oc*2*25;
    #pragma unroll
    for (int ic = 0; ic < 2; ++ic)
        #pragma unroll
        for (int ky = 0; ky < 5; ++ky)
            #pragma unroll
            for (int kx = 0; kx < 5; ++kx)
                s = fmaf(xb[ic*1024 + (oy*2+ky)*32 + (ox*2+kx)],
                         wc[ic*25 + ky*5 + kx], s);
    fea[idx] = fmaxf(s, 0.f);
}

// ---------------------------------------------------------------------------
// primary caps
// ---------------------------------------------------------------------------
__global__ void k_primary(const float* __restrict__ fea,
                          const float* __restrict__ pw, const float* __restrict__ pb,
                          const float* __restrict__ aw, const float* __restrict__ ab,
                          float* __restrict__ M, float* __restrict__ a) {
    int idx = blockIdx.x * blockDim.x + threadIdx.x;
    if (idx >= 16*544*196) return;
    int hw = idx % 196, o = (idx/196) % 544, b = idx/(196*544);
    const float* f = fea + b*32*196 + hw;
    if (o < 512) {
        float s = pb[o];
        #pragma unroll
        for (int c = 0; c < 32; ++c) s = fmaf(f[c*196], pw[o*32+c], s);
        M[(b*512+o)*196 + hw] = s;
    } else {
        int oo = o - 512;
        float s = ab[oo];
        #pragma unroll
        for (int c = 0; c < 32; ++c) s = fmaf(f[c*196], aw[oo*32+c], s);
        a[(b*32+oo)*196 + hw] = 1.f/(1.f + expf(-s));
    }
}

// ---------------------------------------------------------------------------
// patch extraction, p-major: aP[(b*P+p)*ni + i], Mp[((b*P+p)*ni + i)*16]
// ---------------------------------------------------------------------------
__global__ void k_patch(const float* __restrict__ a_in, const float* __restrict__ M_in,
                        float* __restrict__ aP, float* __restrict__ Mp,
                        int B, int K, int stride, int h, int w, int oh, int ow) {
    int P = oh*ow, KK = K*K, ni = B*KK;
    int idx = blockIdx.x * blockDim.x + threadIdx.x;
    if (idx >= 16*ni*P) return;
    int i = idx % ni, p = (idx/ni) % P, b = idx/(ni*P);
    int Bi = i / KK, kk = i % KK, ki = kk / K, kj = kk % K;
    int py = p / ow, px = p % ow;
    int src = (py*stride + ki)*w + (px*stride + kj);
    int hw = h*w;
    aP[idx] = a_in[(b*B + Bi)*hw + src];
    const float* Ms = M_in + (size_t)((b*B + Bi)*16)*hw + src;
    float* Md = Mp + (size_t)idx*16;
    #pragma unroll
    for (int m = 0; m < 16; ++m) Md[m] = Ms[m*hw];
}

// W transpose: Wt[(c*NI+i)*16+m] = W[(i*C+c)*16+m]
__global__ void k_wt(const float* __restrict__ W, float* __restrict__ Wt,
                     int NI, int C) {
    int idx = blockIdx.x * blockDim.x + threadIdx.x;
    if (idx >= NI*C*16) return;
    int m = idx % 16, i = (idx/16) % NI, c = idx/(16*NI);
    Wt[idx] = W[(i*C + c)*16 + m];
}

// ---------------------------------------------------------------------------
// EM stats: 4 waves/block, wave w handles c = cg*4+w; all waves share the
// same (b,p) slice so Mp/aP stream is loaded once into L1 and reused 4x.
// Reads Rt[j][i] contiguously; one-pass E[x^2] variance.
// ---------------------------------------------------------------------------
template<int NI, int NJ, int P, int C>
__global__ __launch_bounds__(256) __attribute__((amdgpu_waves_per_eu(2,4)))
void k_stats(const float* __restrict__ aP, const float* __restrict__ Mp,
             const float* __restrict__ Wt, const float* __restrict__ Rt,
             const float* __restrict__ beta_a, const float* __restrict__ beta_u,
             float* __restrict__ muT, float* __restrict__ isT,
             float2* __restrict__ lsa,
             float* __restrict__ a_fin, float* __restrict__ M_fin,
             int t, float lam, int fin)
{
    constexpr int NIT = (NI + 63) / 64;
    constexpr int BNJ = 16*NJ;
    int wave = threadIdx.x >> 6, lane = threadIdx.x & 63;
    int g  = blockIdx.x % (16*P);
    int cg = blockIdx.x / (16*P);
    int c  = cg*4 + wave;
    int bb = g / P, p = g % P;
    int j  = c*P + p;

    const float* aPb  = aP + (size_t)(bb*P + p)*NI;
    const float* Mpb  = Mp + (size_t)(bb*P + p)*NI*16;
    const float* Wtc  = Wt + (size_t)c*NI*16;
    const float* Rrow = Rt + (size_t)(bb*NJ + j)*NI;

    float accw = 0.f, accm[16], acc2[16];
    #pragma unroll
    for (int m = 0; m < 16; ++m) { accm[m] = 0.f; acc2[m] = 0.f; }

    for (int it = 0; it < NIT; ++it) {
        int i = lane + it*64;
        if ((NI % 64 == 0) || (i < NI)) {
            float r = (t == 0) ? (1.f/NJ) : Rrow[i];
            float wgt = r * aPb[i];
            const float4* Mr = (const float4*)(Mpb + (size_t)i*16);
            const float4* Wr = (const float4*)(Wtc + (size_t)i*16);
            float4 m0 = Mr[0], m1 = Mr[1], m2 = Mr[2], m3 = Mr[3];
            accw += wgt;
            #pragma unroll
            for (int rr = 0; rr < 4; ++rr) {
                float4 w = Wr[rr];
                float v0 = fmaf(w.w, m3.x, fmaf(w.z, m2.x, fmaf(w.y, m1.x, w.x*m0.x)));
                float v1 = fmaf(w.w, m3.y, fmaf(w.z, m2.y, fmaf(w.y, m1.y, w.x*m0.y)));
                float v2 = fmaf(w.w, m3.z, fmaf(w.z, m2.z, fmaf(w.y, m1.z, w.x*m0.z)));
                float v3 = fmaf(w.w, m3.w, fmaf(w.z, m2.w, fmaf(w.y, m1.w, w.x*m0.w)));
                float t0 = wgt*v0, t1 = wgt*v1, t2 = wgt*v2, t3 = wgt*v3;
                accm[rr*4+0] += t0; acc2[rr*4+0] = fmaf(t0, v0, acc2[rr*4+0]);
                accm[rr*4+1] += t1; acc2[rr*4+1] = fmaf(t1, v1, acc2[rr*4+1]);
                accm[rr*4+2] += t2; acc2[rr*4+2] = fmaf(t2, v2, acc2[rr*4+2]);
                accm[rr*4+3] += t3; acc2[rr*4+3] = fmaf(t3, v3, acc2[rr*4+3]);
            }
        }
    }

    for (int off = 1; off < 64; off <<= 1) {
        accw += __shfl_xor(accw, off);
        #pragma unroll
        for (int m = 0; m < 16; ++m) accm[m] += __shfl_xor(accm[m], off);
        #pragma unroll
        for (int m = 0; m < 16; ++m) acc2[m] += __shfl_xor(acc2[m], off);
    }

    float coeff = fmaxf(accw, 1e-8f);
    float lsum = 0.f, mu[16], isv[16];
    #pragma unroll
    for (int m = 0; m < 16; ++m) {
        mu[m] = accm[m] / coeff;
        float s = fmaxf(acc2[m]/coeff - mu[m]*mu[m], 1e-8f);
        lsum += logf(s);
        isv[m] = 1.f / s;
    }
    float ao = 1.f/(1.f + expf(-(lam * (beta_a[j % C] - (16.f*beta_u[j % C] + 0.5f*lsum) * coeff))));

    if (lane == 0) {
        #pragma unroll
        for (int m = 0; m < 16; ++m) {
            muT[m*BNJ + bb*NJ + j] = mu[m];
            isT[m*BNJ + bb*NJ + j] = isv[m];
        }
        lsa[bb*NJ + j] = make_float2(lsum, ao);
        if (fin) {
            a_fin[bb*NJ + j] = ao;
            #pragma unroll
            for (int m = 0; m < 16; ++m)
                M_fin[(size_t)(bb*16 + m)*NJ + j] = mu[m];   // faithful transpose scramble
        }
    }
}

// ---------------------------------------------------------------------------
// R update: one wave per (b,i). softmax over j -> writes Rt[j][i].
// ---------------------------------------------------------------------------
template<int NI, int NJ, int P, int C>
__global__ __launch_bounds__(64) __attribute__((amdgpu_waves_per_eu(2,4)))
void k_R(const float* __restrict__ Mp, const float* __restrict__ W,
         const float* __restrict__ muT, const float* __restrict__ isT,
         const float2* __restrict__ lsa, float* __restrict__ Rt)
{
    constexpr int NJL = (NJ + 63) / 64;
    constexpr int BNJ = 16*NJ;
    constexpr int WS = 20;
    __shared__ float Wl[C*WS];
    __shared__ float Ml[P*WS];
    int i = blockIdx.x % NI, bb = blockIdx.x / NI;
    int lane = threadIdx.x;

    const float* Wsrc = W + (size_t)i*C*16;
    for (int k = lane; k < C*16; k += 64) Wl[(k/16)*WS + (k%16)] = Wsrc[k];
    for (int k = lane; k < P*16; k += 64) {
        int p = k/16, m = k%16;
        Ml[p*WS + m] = Mp[((size_t)(bb*P + p)*NI + i)*16 + m];
    }
    __syncthreads();

    float sv[NJL];
    float mx = -3.0e38f;
    #pragma unroll
    for (int k = 0; k < NJL; ++k) {
        int j = lane + k*64;
        sv[k] = -3.0e38f;
        if ((NJ % 64 == 0) || (j < NJ)) {
            int c = j / P, p = j % P;
            const float4* Mr = (const float4*)(Ml + p*WS);
            const float4* Wr = (const float4*)(Wl + c*WS);
            float4 m0 = Mr[0], m1 = Mr[1], m2 = Mr[2], m3 = Mr[3];
            float q = 0.f;
            #pragma unroll
            for (int rr = 0; rr < 4; ++rr) {
                float4 w = Wr[rr];
                float v0 = fmaf(w.w, m3.x, fmaf(w.z, m2.x, fmaf(w.y, m1.x, w.x*m0.x)));
                float v1 = fmaf(w.w, m3.y, fmaf(w.z, m2.y, fmaf(w.y, m1.y, w.x*m0.y)));
                float v2 = fmaf(w.w, m3.z, fmaf(w.z, m2.z, fmaf(w.y, m1.z, w.x*m0.z)));
                float v3 = fmaf(w.w, m3.w, fmaf(w.z, m2.w, fmaf(w.y, m1.w, w.x*m0.w)));
                float d0 = v0 - muT[(rr*4+0)*BNJ + bb*NJ + j];
                float d1 = v1 - muT[(rr*4+1)*BNJ + bb*NJ + j];
                float d2 = v2 - muT[(rr*4+2)*BNJ + bb*NJ + j];
                float d3 = v3 - muT[(rr*4+3)*BNJ + bb*NJ + j];
                q = fmaf(d0*d0, isT[(rr*4+0)*BNJ + bb*NJ + j], q);
                q = fmaf(d1*d1, isT[(rr*4+1)*BNJ + bb*NJ + j], q);
                q = fmaf(d2*d2, isT[(rr*4+2)*BNJ + bb*NJ + j], q);
                q = fmaf(d3*d3, isT[(rr*4+3)*BNJ + bb*NJ + j], q);
            }
            float2 la = lsa[bb*NJ + j];
            float logp = -0.5f * (16.f*LN2PI + la.x + q);
            sv[k] = la.y * logp;
        }
        mx = fmaxf(mx, sv[k]);
    }
    for (int off = 1; off < 64; off <<= 1) mx = fmaxf(mx, __shfl_xor(mx, off));
    float sm = 0.f;
    #pragma unroll
    for (int k = 0; k < NJL; ++k) {
        int j = lane + k*64;
        if ((NJ % 64 == 0) || (j < NJ)) { sv[k] = expf(sv[k] - mx); sm += sv[k]; }
    }
    for (int off = 1; off < 64; off <<= 1) sm += __shfl_xor(sm, off);
    float inv = 1.f / sm;
    #pragma unroll
    for (int k = 0; k < NJL; ++k) {
        int j = lane + k*64;
        if ((NJ % 64 == 0) || (j < NJ))
            Rt[(size_t)(bb*NJ + j)*NI + i] = sv[k] * inv;
    }
}

// ---------------------------------------------------------------------------
// layer 4 fused: 512 threads; waves 0-4 each own one j (wave-local stats,
// no inter-wave sync); R phase = thread-per-i. sMt stored [m][i] -> LDS
// conflict-free. 3 syncthreads per EM iteration.
// ---------------------------------------------------------------------------
__global__ __launch_bounds__(512) __attribute__((amdgpu_waves_per_eu(2,4)))
void k_layer4(const float* __restrict__ a3, const float* __restrict__ M3,
              const float* __restrict__ W4, const float* __restrict__ ba4,
              const float* __restrict__ bu4, float* __restrict__ out)
{
    __shared__ float sMt[16*512];   // [m][i] 32KB
    __shared__ float sA[512];
    __shared__ float sW[2560];      // [Bi][j][m]
    __shared__ float sR[2560];      // [i][j]
    __shared__ float sStat[5][34];  // mu[16], isig[16], lsum, ao

    int b = blockIdx.x, tid = threadIdx.x;
    int lane = tid & 63, wave = tid >> 6;

    for (int k = tid; k < 8192; k += 512) {
        int i = k & 511, m = k >> 9;
        // faithful channel scramble: M3 flat -> per-i 4x4 pose
        sMt[k] = M3[b*8192 + (i & ~15)*16 + m*16 + (i & 15)];
    }
    sA[tid] = a3[b*512 + tid];
    for (int k = tid; k < 2560; k += 512) { sW[k] = W4[k]; sR[k] = 0.2f; }
    __syncthreads();

    const float lams[3] = {5.0e-4f, 9.75e-4f, 1.426250e-3f};

    for (int t = 0; t < 3; ++t) {
        if (wave < 5) {
            int j = wave;
            float accw = 0.f, accm[16], acc2[16];
            #pragma unroll
            for (int m = 0; m < 16; ++m) { accm[m] = 0.f; acc2[m] = 0.f; }
            for (int u = 0; u < 8; ++u) {
                int i = u*64 + lane;
                float wgt = sR[i*5 + j] * sA[i];
                float Mm[16];
                #pragma unroll
                for (int m = 0; m < 16; ++m) Mm[m] = sMt[m*512 + i];
                const float* Wm = &sW[((i>>4)*5 + j)*16];
                float V[16];
                #pragma unroll
                for (int r = 0; r < 4; ++r)
                    #pragma unroll
                    for (int cc = 0; cc < 4; ++cc) {
                        float s = Wm[r*4+0]*Mm[0*4+cc];
                        s = fmaf(Wm[r*4+1], Mm[1*4+cc], s);
                        s = fmaf(Wm[r*4+2], Mm[2*4+cc], s);
                        s = fmaf(Wm[r*4+3], Mm[3*4+cc], s);
                        V[r*4+cc] = s;
                    }
                V[0] += (float)((i & 15) >> 2) * 0.25f;
                V[1] += (float)(i & 3) * 0.25f;
                accw += wgt;
                #pragma unroll
                for (int m = 0; m < 16; ++m) {
                    float t1 = wgt * V[m];
                    accm[m] += t1;
                    acc2[m] = fmaf(t1, V[m], acc2[m]);
                }
            }
            for (int off = 1; off < 64; off <<= 1) {
                accw += __shfl_xor(accw, off);
                #pragma unroll
                for (int m = 0; m < 16; ++m) accm[m] += __shfl_xor(accm[m], off);
                #pragma unroll
                for (int m = 0; m < 16; ++m) acc2[m] += __shfl_xor(acc2[m], off);
            }
            float coeff = fmaxf(accw, 1e-8f);
            float lsum = 0.f, mu[16], isv[16];
            #pragma unroll
            for (int m = 0; m < 16; ++m) {
                mu[m] = accm[m] / coeff;
                float s = fmaxf(acc2[m]/coeff - mu[m]*mu[m], 1e-8f);
                lsum += logf(s);
                isv[m] = 1.f / s;
            }
            float ao = 1.f/(1.f + expf(-(lams[t] * (ba4[j] - (16.f*bu4[j] + 0.5f*lsum) * coeff))));
            if (lane == 0) {
                #pragma unroll
                for (int m = 0; m < 16; ++m) { sStat[j][m] = mu[m]; sStat[j][16+m] = isv[m]; }
                sStat[j][32] = lsum; sStat[j][33] = ao;
            }
        }
        __syncthreads();
        if (t < 2) {
            int i = tid;
            float Mm[16];
            #pragma unroll
            for (int m = 0; m < 16; ++m) Mm[m] = sMt[m*512 + i];
            float sv[5], mxv = -3.0e38f;
            #pragma unroll
            for (int j = 0; j < 5; ++j) {
                const float* Wm = &sW[((i>>4)*5 + j)*16];
                float V[16];
                #pragma unroll
                for (int r = 0; r < 4; ++r)
                    #pragma unroll
                    for (int cc = 0; cc < 4; ++cc) {
                        float s = Wm[r*4+0]*Mm[0*4+cc];
                        s = fmaf(Wm[r*4+1], Mm[1*4+cc], s);
                        s = fmaf(Wm[r*4+2], Mm[2*4+cc], s);
                        s = fmaf(Wm[r*4+3], Mm[3*4+cc], s);
                        V[r*4+cc] = s;
                    }
                V[0] += (float)((i & 15) >> 2) * 0.25f;
                V[1] += (float)(i & 3) * 0.25f;
                float q = 0.f;
                #pragma unroll
                for (int m = 0; m < 16; ++m) {
                    float d = V[m] - sStat[j][m];
                    q = fmaf(d*d, sStat[j][16+m], q);
                }
                float logp = -0.5f * (16.f*LN2PI + sStat[j][32] + q);
                sv[j] = sStat[j][33] * logp;
                mxv = fmaxf(mxv, sv[j]);
            }
            float sum = 0.f;
            #pragma unroll
            for (int j = 0; j < 5; ++j) { sv[j] = expf(sv[j] - mxv); sum += sv[j]; }
            float inv = 1.f / sum;
            #pragma unroll
            for (int j = 0; j < 5; ++j) sR[i*5 + j] = sv[j] * inv;
            __syncthreads();
        }
    }
    if (tid < 5) out[b*5 + tid] = sStat[tid][33];
}

// ---------------------------------------------------------------------------
// host: one EM layer (layers 2/3)
// ---------------------------------------------------------------------------
template<int NI, int NJ, int P, int C>
static void run_em(hipStream_t stream,
                   const float* aP, const float* Mp, const float* W, const float* Wt,
                   const float* ba, const float* bu, float* Rt,
                   float* muT, float* isT, float2* lsa,
                   float* a_fin, float* M_fin)
{
    const float lams[3] = {5.0e-4f, 9.75e-4f, 1.426250e-3f};
    for (int t = 0; t < 3; ++t) {
        k_stats<NI,NJ,P,C><<<16*NJ/4, 256, 0, stream>>>(
            aP, Mp, Wt, Rt, ba, bu, muT, isT, lsa, a_fin, M_fin,
            t, lams[t], (t == 2) ? 1 : 0);
        if (t < 2) {
            k_R<NI,NJ,P,C><<<16*NI, 64, 0, stream>>>(
                Mp, W, muT, isT, lsa, Rt);
        }
    }
}

extern "C" void kernel_launch(void* const* d_in, const int* in_sizes, int n_in,
                              void* d_out, int out_size, void* d_ws, size_t ws_size,
                              hipStream_t stream) {
    (void)in_sizes; (void)n_in; (void)out_size; (void)ws_size;
    const float* x       = (const float*)d_in[0];
    const float* conv_w  = (const float*)d_in[1];
    const float* conv_b  = (const float*)d_in[2];
    const float* pose_w  = (const float*)d_in[3];
    const float* pose_b  = (const float*)d_in[4];
    const float* act_w   = (const float*)d_in[5];
    const float* act_b   = (const float*)d_in[6];
    const float* W2      = (const float*)d_in[7];
    const float* beta_a2 = (const float*)d_in[8];
    const float* beta_u2 = (const float*)d_in[9];
    const float* W3      = (const float*)d_in[10];
    const float* beta_a3 = (const float*)d_in[11];
    const float* beta_u3 = (const float*)d_in[12];
    const float* W4      = (const float*)d_in[13];
    const float* beta_a4 = (const float*)d_in[14];
    const float* beta_u4 = (const float*)d_in[15];

    // workspace layout (floats), ~44.6 MB total
    float* ws   = (float*)d_ws;
    float* fea  = ws;                    // 100352
    float* a1   = fea  + 100352;         // 100352
    float* M1   = a1   + 100352;         // 1605632
    float* aP   = M1   + 1605632;        // 165888 (max)
    float* Mp   = aP   + 165888;         // 2654208 (max)
    float* Wt   = Mp   + 2654208;        // 147456
    float* muT  = Wt   + 147456;         // 294912 (16 x 16*1152)
    float* isT  = muT  + 294912;         // 294912
    float* lsa  = isT  + 294912;         // 36864 (float2 x 18432)
    float* Rt   = lsa  + 36864;          // 5308416 (max 16*1152*288)
    float* a2   = Rt   + 5308416;        // 18432
    float* M2   = a2   + 18432;          // 294912
    float* a3   = M2   + 294912;         // 8192
    float* M3   = a3   + 8192;           // 131072

    // stem + primary caps
    k_stem<<<(16*32*196 + 255)/256, 256, 0, stream>>>(x, conv_w, conv_b, fea);
    k_primary<<<(16*544*196 + 255)/256, 256, 0, stream>>>(fea, pose_w, pose_b,
                                                          act_w, act_b, M1, a1);

    // layer 2: NI=288, NJ=1152, P=36, C=32
    k_patch<<<(16*288*36 + 255)/256, 256, 0, stream>>>(a1, M1, aP, Mp, 32, 3, 2, 14, 14, 6, 6);
    k_wt<<<(288*32*16 + 255)/256, 256, 0, stream>>>(W2, Wt, 288, 32);
    run_em<288,1152,36,32>(stream, aP, Mp, W2, Wt, beta_a2, beta_u2, Rt,
                           muT, isT, (float2*)lsa, a2, M2);

    // layer 3: NI=288, NJ=512, P=16, C=32
    k_patch<<<(16*288*16 + 255)/256, 256, 0, stream>>>(a2, M2, aP, Mp, 32, 3, 1, 6, 6, 4, 4);
    k_wt<<<(288*32*16 + 255)/256, 256, 0, stream>>>(W3, Wt, 288, 32);
    run_em<288,512,16,32>(stream, aP, Mp, W3, Wt, beta_a3, beta_u3, Rt,
                          muT, isT, (float2*)lsa, a3, M3);

    // layer 4 fused
    k_layer4<<<16, 512, 0, stream>>>(a3, M3, W4, beta_a4, beta_u4, (float*)d_out);
}

// Round 7
// 666.843 us; speedup vs baseline: 4.4133x; 1.1089x over previous
//
#include <hip/hip_runtime.h>
#include <math.h>

#define LN2PI 1.83787706640934548356f

// ---------------------------------------------------------------------------
// stem: conv 5x5 stride 2 valid + bias + relu : (16,2,32,32) -> (16,32,14,14)
// ---------------------------------------------------------------------------
__global__ void k_stem(const float* __restrict__ x, const float* __restrict__ w,
                       const float* __restrict__ bias, float* __restrict__ fea) {
    int idx = blockIdx.x * blockDim.x + threadIdx.x;
    if (idx >= 16*32*14*14) return;
    int ox = idx % 14, oy = (idx/14) % 14, oc = (idx/196) % 32, b = idx/(196*32);
    float s = bias[oc];
    const float* xb = x + b*2*1024;
    const float* wc = w + oc*2*25;
    #pragma unroll
    for (int ic = 0; ic < 2; ++ic)
        #pragma unroll
        for (int ky = 0; ky < 5; ++ky)
            #pragma unroll
            for (int kx = 0; kx < 5; ++kx)
                s = fmaf(xb[ic*1024 + (oy*2+ky)*32 + (ox*2+kx)],
                         wc[ic*25 + ky*5 + kx], s);
    fea[idx] = fmaxf(s, 0.f);
}

// ---------------------------------------------------------------------------
// primary caps
// ---------------------------------------------------------------------------
__global__ void k_primary(const float* __restrict__ fea,
                          const float* __restrict__ pw, const float* __restrict__ pb,
                          const float* __restrict__ aw, const float* __restrict__ ab,
                          float* __restrict__ M, float* __restrict__ a) {
    int idx = blockIdx.x * blockDim.x + threadIdx.x;
    if (idx >= 16*544*196) return;
    int hw = idx % 196, o = (idx/196) % 544, b = idx/(196*544);
    const float* f = fea + b*32*196 + hw;
    if (o < 512) {
        float s = pb[o];
        #pragma unroll
        for (int c = 0; c < 32; ++c) s = fmaf(f[c*196], pw[o*32+c], s);
        M[(b*512+o)*196 + hw] = s;
    } else {
        int oo = o - 512;
        float s = ab[oo];
        #pragma unroll
        for (int c = 0; c < 32; ++c) s = fmaf(f[c*196], aw[oo*32+c], s);
        a[(b*32+oo)*196 + hw] = 1.f/(1.f + expf(-s));
    }
}

// ---------------------------------------------------------------------------
// patch extraction, p-major: aP[(b*P+p)*ni + i], Mp[((b*P+p)*ni + i)*16]
// ---------------------------------------------------------------------------
__global__ void k_patch(const float* __restrict__ a_in, const float* __restrict__ M_in,
                        float* __restrict__ aP, float* __restrict__ Mp,
                        int B, int K, int stride, int h, int w, int oh, int ow) {
    int P = oh*ow, KK = K*K, ni = B*KK;
    int idx = blockIdx.x * blockDim.x + threadIdx.x;
    if (idx >= 16*ni*P) return;
    int i = idx % ni, p = (idx/ni) % P, b = idx/(ni*P);
    int Bi = i / KK, kk = i % KK, ki = kk / K, kj = kk % K;
    int py = p / ow, px = p % ow;
    int src = (py*stride + ki)*w + (px*stride + kj);
    int hw = h*w;
    aP[idx] = a_in[(b*B + Bi)*hw + src];
    const float* Ms = M_in + (size_t)((b*B + Bi)*16)*hw + src;
    float* Md = Mp + (size_t)idx*16;
    #pragma unroll
    for (int m = 0; m < 16; ++m) Md[m] = Ms[m*hw];
}

// W transpose: Wt[(c*NI+i)*16+m] = W[(i*C+c)*16+m]
__global__ void k_wt(const float* __restrict__ W, float* __restrict__ Wt,
                     int NI, int C) {
    int idx = blockIdx.x * blockDim.x + threadIdx.x;
    if (idx >= NI*C*16) return;
    int m = idx % 16, i = (idx/16) % NI, c = idx/(16*NI);
    Wt[idx] = W[(i*C + c)*16 + m];
}

// ---------------------------------------------------------------------------
// EM stats: 4 waves/block, wave w -> c = cg*4+w, shared (b,p) slice.
// t>0: r = exp(sv - mx_i) * ism_i  (deferred softmax normalization).
// Stores PACKED stats for k_sv: G[16], H2[16], K1 (36-float row).
// ---------------------------------------------------------------------------
template<int NI, int NJ, int P, int C>
__global__ __launch_bounds__(256) __attribute__((amdgpu_waves_per_eu(2,4)))
void k_stats(const float* __restrict__ aP, const float* __restrict__ Mp,
             const float* __restrict__ Wt, const float* __restrict__ svb,
             const float* __restrict__ mxs, const float* __restrict__ ism,
             const float* __restrict__ beta_a, const float* __restrict__ beta_u,
             float* __restrict__ statP,
             float* __restrict__ a_fin, float* __restrict__ M_fin,
             int t, float lam, int fin)
{
    constexpr int NIT = (NI + 63) / 64;
    int wave = threadIdx.x >> 6, lane = threadIdx.x & 63;
    int g  = blockIdx.x % (16*P);
    int cg = blockIdx.x / (16*P);
    int c  = cg*4 + wave;
    int bb = g / P, p = g % P;
    int j  = c*P + p;

    const float* aPb  = aP + (size_t)(bb*P + p)*NI;
    const float* Mpb  = Mp + (size_t)(bb*P + p)*NI*16;
    const float* Wtc  = Wt + (size_t)c*NI*16;
    const float* svr  = svb + (size_t)(bb*NJ + j)*NI;
    const float* mxb  = mxs + bb*NI;
    const float* imb  = ism + bb*NI;

    float accw = 0.f, accm[16], acc2[16];
    #pragma unroll
    for (int m = 0; m < 16; ++m) { accm[m] = 0.f; acc2[m] = 0.f; }

    for (int it = 0; it < NIT; ++it) {
        int i = lane + it*64;
        if ((NI % 64 == 0) || (i < NI)) {
            float r;
            if (t == 0) r = 1.f / NJ;
            else        r = expf(svr[i] - mxb[i]) * imb[i];
            float wgt = r * aPb[i];
            const float4* Mr = (const float4*)(Mpb + (size_t)i*16);
            const float4* Wr = (const float4*)(Wtc + (size_t)i*16);
            float4 m0 = Mr[0], m1 = Mr[1], m2 = Mr[2], m3 = Mr[3];
            accw += wgt;
            #pragma unroll
            for (int rr = 0; rr < 4; ++rr) {
                float4 w = Wr[rr];
                float v0 = fmaf(w.w, m3.x, fmaf(w.z, m2.x, fmaf(w.y, m1.x, w.x*m0.x)));
                float v1 = fmaf(w.w, m3.y, fmaf(w.z, m2.y, fmaf(w.y, m1.y, w.x*m0.y)));
                float v2 = fmaf(w.w, m3.z, fmaf(w.z, m2.z, fmaf(w.y, m1.z, w.x*m0.z)));
                float v3 = fmaf(w.w, m3.w, fmaf(w.z, m2.w, fmaf(w.y, m1.w, w.x*m0.w)));
                float t0 = wgt*v0, t1 = wgt*v1, t2 = wgt*v2, t3 = wgt*v3;
                accm[rr*4+0] += t0; acc2[rr*4+0] = fmaf(t0, v0, acc2[rr*4+0]);
                accm[rr*4+1] += t1; acc2[rr*4+1] = fmaf(t1, v1, acc2[rr*4+1]);
                accm[rr*4+2] += t2; acc2[rr*4+2] = fmaf(t2, v2, acc2[rr*4+2]);
                accm[rr*4+3] += t3; acc2[rr*4+3] = fmaf(t3, v3, acc2[rr*4+3]);
            }
        }
    }

    for (int off = 1; off < 64; off <<= 1) {
        accw += __shfl_xor(accw, off);
        #pragma unroll
        for (int m = 0; m < 16; ++m) accm[m] += __shfl_xor(accm[m], off);
        #pragma unroll
        for (int m = 0; m < 16; ++m) acc2[m] += __shfl_xor(acc2[m], off);
    }

    float coeff = fmaxf(accw, 1e-8f);
    float lsum = 0.f, mu[16], isv[16];
    #pragma unroll
    for (int m = 0; m < 16; ++m) {
        mu[m] = accm[m] / coeff;
        float s = fmaxf(acc2[m]/coeff - mu[m]*mu[m], 1e-8f);
        lsum += logf(s);
        isv[m] = 1.f / s;
    }
    float ao = 1.f/(1.f + expf(-(lam * (beta_a[j % C] - (16.f*beta_u[j % C] + 0.5f*lsum) * coeff))));

    if (lane == 0) {
        float* st = statP + (size_t)(bb*NJ + j)*36;
        float K1 = -0.5f*ao*(16.f*LN2PI + lsum);
        #pragma unroll
        for (int m = 0; m < 16; ++m) {
            float Gm = -0.5f*ao*isv[m];
            st[m]      = Gm;
            st[16+m]   = -2.f*Gm*mu[m];
            K1 = fmaf(Gm*mu[m], mu[m], K1);
        }
        st[32] = K1;
        if (fin) {
            a_fin[bb*NJ + j] = ao;
            #pragma unroll
            for (int m = 0; m < 16; ++m)
                M_fin[(size_t)(bb*16 + m)*NJ + j] = mu[m];   // faithful transpose scramble
        }
    }
}

// ---------------------------------------------------------------------------
// k_sv: lane = i. Block = 320 thr (5 waves) covers NI=288 (tail masked),
// one (b, j-chunk). Computes sv = ao*logp via packed stats
// (sv = K1 + sum_m V*fma(V,G,H2)), ONLINE per-lane max/sum, writes sv
// COALESCED to svb[j][i], partial (mx,sm) per chunk. No LDS, no shuffles.
// ---------------------------------------------------------------------------
template<int NI, int NJ, int P, int JC>
__global__ __launch_bounds__(320)
void k_sv(const float* __restrict__ Mp, const float* __restrict__ Wt,
          const float* __restrict__ statP,
          float* __restrict__ svb, float* __restrict__ pmx, float* __restrict__ psm)
{
    constexpr int NCH = NJ / JC;
    int ch = blockIdx.x % NCH, bb = blockIdx.x / NCH;
    int i = threadIdx.x;
    bool act = (i < NI);
    int j0 = ch * JC;
    int c = j0 / P, p = j0 % P;

    const float* Mpb = Mp + (size_t)(bb*P)*NI*16;
    float4 w0, w1, w2, w3;
    bool wload = true;
    float mx = -3.0e38f, sm = 0.f;

    for (int jj = 0; jj < JC; ++jj) {
        int j = j0 + jj;
        const float* st = statP + (size_t)(bb*NJ + j)*36;   // uniform across block
        if (act) {
            if (wload) {
                const float4* Wr = (const float4*)(Wt + ((size_t)c*NI + i)*16);
                w0 = Wr[0]; w1 = Wr[1]; w2 = Wr[2]; w3 = Wr[3];
            }
            const float4* Mr = (const float4*)(Mpb + ((size_t)p*NI + i)*16);
            float4 m0 = Mr[0], m1 = Mr[1], m2 = Mr[2], m3 = Mr[3];
            float V[16];
            {
                float4 w = w0;
                V[0] = fmaf(w.w, m3.x, fmaf(w.z, m2.x, fmaf(w.y, m1.x, w.x*m0.x)));
                V[1] = fmaf(w.w, m3.y, fmaf(w.z, m2.y, fmaf(w.y, m1.y, w.x*m0.y)));
                V[2] = fmaf(w.w, m3.z, fmaf(w.z, m2.z, fmaf(w.y, m1.z, w.x*m0.z)));
                V[3] = fmaf(w.w, m3.w, fmaf(w.z, m2.w, fmaf(w.y, m1.w, w.x*m0.w)));
                w = w1;
                V[4] = fmaf(w.w, m3.x, fmaf(w.z, m2.x, fmaf(w.y, m1.x, w.x*m0.x)));
                V[5] = fmaf(w.w, m3.y, fmaf(w.z, m2.y, fmaf(w.y, m1.y, w.x*m0.y)));
                V[6] = fmaf(w.w, m3.z, fmaf(w.z, m2.z, fmaf(w.y, m1.z, w.x*m0.z)));
                V[7] = fmaf(w.w, m3.w, fmaf(w.z, m2.w, fmaf(w.y, m1.w, w.x*m0.w)));
                w = w2;
                V[8]  = fmaf(w.w, m3.x, fmaf(w.z, m2.x, fmaf(w.y, m1.x, w.x*m0.x)));
                V[9]  = fmaf(w.w, m3.y, fmaf(w.z, m2.y, fmaf(w.y, m1.y, w.x*m0.y)));
                V[10] = fmaf(w.w, m3.z, fmaf(w.z, m2.z, fmaf(w.y, m1.z, w.x*m0.z)));
                V[11] = fmaf(w.w, m3.w, fmaf(w.z, m2.w, fmaf(w.y, m1.w, w.x*m0.w)));
                w = w3;
                V[12] = fmaf(w.w, m3.x, fmaf(w.z, m2.x, fmaf(w.y, m1.x, w.x*m0.x)));
                V[13] = fmaf(w.w, m3.y, fmaf(w.z, m2.y, fmaf(w.y, m1.y, w.x*m0.y)));
                V[14] = fmaf(w.w, m3.z, fmaf(w.z, m2.z, fmaf(w.y, m1.z, w.x*m0.z)));
                V[15] = fmaf(w.w, m3.w, fmaf(w.z, m2.w, fmaf(w.y, m1.w, w.x*m0.w)));
            }
            float acc = 0.f;
            #pragma unroll
            for (int m = 0; m < 16; ++m) {
                float tmp = fmaf(V[m], st[m], st[16+m]);
                acc = fmaf(V[m], tmp, acc);
            }
            float sv = st[32] + acc;
            if (sv > mx) { sm = sm*expf(mx - sv) + 1.f; mx = sv; }
            else         { sm += expf(sv - mx); }
            svb[(size_t)(bb*NJ + j)*NI + i] = sv;
        }
        ++p;
        if (p == P) { p = 0; ++c; wload = true; } else wload = false;
    }
    if (act) {
        pmx[(size_t)ch*(16*NI) + bb*NI + i] = mx;
        psm[(size_t)ch*(16*NI) + bb*NI + i] = sm;
    }
}

// ---------------------------------------------------------------------------
// combine chunk partials -> mxs, ism (per (b,i))
// ---------------------------------------------------------------------------
__global__ void k_comb(const float* __restrict__ pmx, const float* __restrict__ psm,
                       float* __restrict__ mxs, float* __restrict__ ism,
                       int nch, int ntot)
{
    int idx = blockIdx.x * blockDim.x + threadIdx.x;
    if (idx >= ntot) return;
    float mx = -3.0e38f, sm = 0.f;
    for (int ch = 0; ch < nch; ++ch) {
        float m2 = pmx[(size_t)ch*ntot + idx];
        float s2 = psm[(size_t)ch*ntot + idx];
        float M = fmaxf(mx, m2);
        sm = sm*expf(mx - M) + s2*expf(m2 - M);
        mx = M;
    }
    mxs[idx] = mx;
    ism[idx] = 1.f / sm;
}

// ---------------------------------------------------------------------------
// layer 4 fused (round-6, verified): 512 thr; waves 0-4 own one j each.
// ---------------------------------------------------------------------------
__global__ __launch_bounds__(512) __attribute__((amdgpu_waves_per_eu(2,4)))
void k_layer4(const float* __restrict__ a3, const float* __restrict__ M3,
              const float* __restrict__ W4, const float* __restrict__ ba4,
              const float* __restrict__ bu4, float* __restrict__ out)
{
    __shared__ float sMt[16*512];
    __shared__ float sA[512];
    __shared__ float sW[2560];
    __shared__ float sR[2560];
    __shared__ float sStat[5][34];

    int b = blockIdx.x, tid = threadIdx.x;
    int lane = tid & 63, wave = tid >> 6;

    for (int k = tid; k < 8192; k += 512) {
        int i = k & 511, m = k >> 9;
        sMt[k] = M3[b*8192 + (i & ~15)*16 + m*16 + (i & 15)];
    }
    sA[tid] = a3[b*512 + tid];
    for (int k = tid; k < 2560; k += 512) { sW[k] = W4[k]; sR[k] = 0.2f; }
    __syncthreads();

    const float lams[3] = {5.0e-4f, 9.75e-4f, 1.426250e-3f};

    for (int t = 0; t < 3; ++t) {
        if (wave < 5) {
            int j = wave;
            float accw = 0.f, accm[16], acc2[16];
            #pragma unroll
            for (int m = 0; m < 16; ++m) { accm[m] = 0.f; acc2[m] = 0.f; }
            for (int u = 0; u < 8; ++u) {
                int i = u*64 + lane;
                float wgt = sR[i*5 + j] * sA[i];
                float Mm[16];
                #pragma unroll
                for (int m = 0; m < 16; ++m) Mm[m] = sMt[m*512 + i];
                const float* Wm = &sW[((i>>4)*5 + j)*16];
                float V[16];
                #pragma unroll
                for (int r = 0; r < 4; ++r)
                    #pragma unroll
                    for (int cc = 0; cc < 4; ++cc) {
                        float s = Wm[r*4+0]*Mm[0*4+cc];
                        s = fmaf(Wm[r*4+1], Mm[1*4+cc], s);
                        s = fmaf(Wm[r*4+2], Mm[2*4+cc], s);
                        s = fmaf(Wm[r*4+3], Mm[3*4+cc], s);
                        V[r*4+cc] = s;
                    }
                V[0] += (float)((i & 15) >> 2) * 0.25f;
                V[1] += (float)(i & 3) * 0.25f;
                accw += wgt;
                #pragma unroll
                for (int m = 0; m < 16; ++m) {
                    float t1 = wgt * V[m];
                    accm[m] += t1;
                    acc2[m] = fmaf(t1, V[m], acc2[m]);
                }
            }
            for (int off = 1; off < 64; off <<= 1) {
                accw += __shfl_xor(accw, off);
                #pragma unroll
                for (int m = 0; m < 16; ++m) accm[m] += __shfl_xor(accm[m], off);
                #pragma unroll
                for (int m = 0; m < 16; ++m) acc2[m] += __shfl_xor(acc2[m], off);
            }
            float coeff = fmaxf(accw, 1e-8f);
            float lsum = 0.f, mu[16], isv[16];
            #pragma unroll
            for (int m = 0; m < 16; ++m) {
                mu[m] = accm[m] / coeff;
                float s = fmaxf(acc2[m]/coeff - mu[m]*mu[m], 1e-8f);
                lsum += logf(s);
                isv[m] = 1.f / s;
            }
            float ao = 1.f/(1.f + expf(-(lams[t] * (ba4[j] - (16.f*bu4[j] + 0.5f*lsum) * coeff))));
            if (lane == 0) {
                #pragma unroll
                for (int m = 0; m < 16; ++m) { sStat[j][m] = mu[m]; sStat[j][16+m] = isv[m]; }
                sStat[j][32] = lsum; sStat[j][33] = ao;
            }
        }
        __syncthreads();
        if (t < 2) {
            int i = tid;
            float Mm[16];
            #pragma unroll
            for (int m = 0; m < 16; ++m) Mm[m] = sMt[m*512 + i];
            float sv[5], mxv = -3.0e38f;
            #pragma unroll
            for (int j = 0; j < 5; ++j) {
                const float* Wm = &sW[((i>>4)*5 + j)*16];
                float V[16];
                #pragma unroll
                for (int r = 0; r < 4; ++r)
                    #pragma unroll
                    for (int cc = 0; cc < 4; ++cc) {
                        float s = Wm[r*4+0]*Mm[0*4+cc];
                        s = fmaf(Wm[r*4+1], Mm[1*4+cc], s);
                        s = fmaf(Wm[r*4+2], Mm[2*4+cc], s);
                        s = fmaf(Wm[r*4+3], Mm[3*4+cc], s);
                        V[r*4+cc] = s;
                    }
                V[0] += (float)((i & 15) >> 2) * 0.25f;
                V[1] += (float)(i & 3) * 0.25f;
                float q = 0.f;
                #pragma unroll
                for (int m = 0; m < 16; ++m) {
                    float d = V[m] - sStat[j][m];
                    q = fmaf(d*d, sStat[j][16+m], q);
                }
                float logp = -0.5f * (16.f*LN2PI + sStat[j][32] + q);
                sv[j] = sStat[j][33] * logp;
                mxv = fmaxf(mxv, sv[j]);
            }
            float sum = 0.f;
            #pragma unroll
            for (int j = 0; j < 5; ++j) { sv[j] = expf(sv[j] - mxv); sum += sv[j]; }
            float inv = 1.f / sum;
            #pragma unroll
            for (int j = 0; j < 5; ++j) sR[i*5 + j] = sv[j] * inv;
            __syncthreads();
        }
    }
    if (tid < 5) out[b*5 + tid] = sStat[tid][33];
}

// ---------------------------------------------------------------------------
// host: one EM layer (layers 2/3)
// ---------------------------------------------------------------------------
template<int NI, int NJ, int P, int C, int JC>
static void run_em(hipStream_t stream,
                   const float* aP, const float* Mp, const float* Wt,
                   const float* ba, const float* bu,
                   float* statP, float* svb, float* mxs, float* ism,
                   float* pmx, float* psm,
                   float* a_fin, float* M_fin)
{
    constexpr int NCH = NJ / JC;
    const float lams[3] = {5.0e-4f, 9.75e-4f, 1.426250e-3f};
    for (int t = 0; t < 3; ++t) {
        k_stats<NI,NJ,P,C><<<16*NJ/4, 256, 0, stream>>>(
            aP, Mp, Wt, svb, mxs, ism, ba, bu, statP, a_fin, M_fin,
            t, lams[t], (t == 2) ? 1 : 0);
        if (t < 2) {
            k_sv<NI,NJ,P,JC><<<16*NCH, 320, 0, stream>>>(Mp, Wt, statP, svb, pmx, psm);
            k_comb<<<(16*NI + 255)/256, 256, 0, stream>>>(pmx, psm, mxs, ism, NCH, 16*NI);
        }
    }
}

extern "C" void kernel_launch(void* const* d_in, const int* in_sizes, int n_in,
                              void* d_out, int out_size, void* d_ws, size_t ws_size,
                              hipStream_t stream) {
    (void)in_sizes; (void)n_in; (void)out_size; (void)ws_size;
    const float* x       = (const float*)d_in[0];
    const float* conv_w  = (const float*)d_in[1];
    const float* conv_b  = (const float*)d_in[2];
    const float* pose_w  = (const float*)d_in[3];
    const float* pose_b  = (const float*)d_in[4];
    const float* act_w   = (const float*)d_in[5];
    const float* act_b   = (const float*)d_in[6];
    const float* W2      = (const float*)d_in[7];
    const float* beta_a2 = (const float*)d_in[8];
    const float* beta_u2 = (const float*)d_in[9];
    const float* W3      = (const float*)d_in[10];
    const float* beta_a3 = (const float*)d_in[11];
    const float* beta_u3 = (const float*)d_in[12];
    const float* W4      = (const float*)d_in[13];
    const float* beta_a4 = (const float*)d_in[14];
    const float* beta_u4 = (const float*)d_in[15];

    // workspace layout (floats), ~46.2 MB total
    float* ws    = (float*)d_ws;
    float* fea   = ws;                    // 100352
    float* a1    = fea   + 100352;        // 100352
    float* M1    = a1    + 100352;        // 1605632
    float* aP    = M1    + 1605632;       // 165888 (max)
    float* Mp    = aP    + 165888;        // 2654208 (max)
    float* Wt    = Mp    + 2654208;       // 147456
    float* statP = Wt    + 147456;        // 663552 (16*1152*36)
    float* svb   = statP + 663552;        // 5308416 (16*1152*288)
    float* mxs   = svb   + 5308416;       // 4608
    float* ismb  = mxs   + 4608;          // 4608
    float* pmx   = ismb  + 4608;          // 165888 (36*4608 max)
    float* psm   = pmx   + 165888;        // 165888
    float* a2    = psm   + 165888;        // 18432
    float* M2    = a2    + 18432;         // 294912
    float* a3    = M2    + 294912;        // 8192
    float* M3    = a3    + 8192;          // 131072

    // stem + primary caps
    k_stem<<<(16*32*196 + 255)/256, 256, 0, stream>>>(x, conv_w, conv_b, fea);
    k_primary<<<(16*544*196 + 255)/256, 256, 0, stream>>>(fea, pose_w, pose_b,
                                                          act_w, act_b, M1, a1);

    // layer 2: NI=288, NJ=1152, P=36, C=32, JC=32 (36 chunks)
    k_patch<<<(16*288*36 + 255)/256, 256, 0, stream>>>(a1, M1, aP, Mp, 32, 3, 2, 14, 14, 6, 6);
    k_wt<<<(288*32*16 + 255)/256, 256, 0, stream>>>(W2, Wt, 288, 32);
    run_em<288,1152,36,32,32>(stream, aP, Mp, Wt, beta_a2, beta_u2,
                              statP, svb, mxs, ismb, pmx, psm, a2, M2);

    // layer 3: NI=288, NJ=512, P=16, C=32, JC=16 (32 chunks)
    k_patch<<<(16*288*16 + 255)/256, 256, 0, stream>>>(a2, M2, aP, Mp, 32, 3, 1, 6, 6, 4, 4);
    k_wt<<<(288*32*16 + 255)/256, 256, 0, stream>>>(W3, Wt, 288, 32);
    run_em<288,512,16,32,16>(stream, aP, Mp, Wt, beta_a3, beta_u3,
                             statP, svb, mxs, ismb, pmx, psm, a3, M3);

    // layer 4 fused
    k_layer4<<<16, 512, 0, stream>>>(a3, M3, W4, beta_a4, beta_u4, (float*)d_out);
}

// Round 8
// 489.989 us; speedup vs baseline: 6.0062x; 1.3609x over previous
//
#include <hip/hip_runtime.h>
#include <math.h>

#define LN2PI 1.83787706640934548356f

// ---------------------------------------------------------------------------
// stem: conv 5x5 stride 2 valid + bias + relu : (16,2,32,32) -> (16,32,14,14)
// ---------------------------------------------------------------------------
__global__ void k_stem(const float* __restrict__ x, const float* __restrict__ w,
                       const float* __restrict__ bias, float* __restrict__ fea) {
    int idx = blockIdx.x * blockDim.x + threadIdx.x;
    if (idx >= 16*32*14*14) return;
    int ox = idx % 14, oy = (idx/14) % 14, oc = (idx/196) % 32, b = idx/(196*32);
    float s = bias[oc];
    const float* xb = x + b*2*1024;
    const float* wc = w + oc*2*25;
    #pragma unroll
    for (int ic = 0; ic < 2; ++ic)
        #pragma unroll
        for (int ky = 0; ky < 5; ++ky)
            #pragma unroll
            for (int kx = 0; kx < 5; ++kx)
                s = fmaf(xb[ic*1024 + (oy*2+ky)*32 + (ox*2+kx)],
                         wc[ic*25 + ky*5 + kx], s);
    fea[idx] = fmaxf(s, 0.f);
}

// ---------------------------------------------------------------------------
// primary caps
// ---------------------------------------------------------------------------
__global__ void k_primary(const float* __restrict__ fea,
                          const float* __restrict__ pw, const float* __restrict__ pb,
                          const float* __restrict__ aw, const float* __restrict__ ab,
                          float* __restrict__ M, float* __restrict__ a) {
    int idx = blockIdx.x * blockDim.x + threadIdx.x;
    if (idx >= 16*544*196) return;
    int hw = idx % 196, o = (idx/196) % 544, b = idx/(196*544);
    const float* f = fea + b*32*196 + hw;
    if (o < 512) {
        float s = pb[o];
        #pragma unroll
        for (int c = 0; c < 32; ++c) s = fmaf(f[c*196], pw[o*32+c], s);
        M[(b*512+o)*196 + hw] = s;
    } else {
        int oo = o - 512;
        float s = ab[oo];
        #pragma unroll
        for (int c = 0; c < 32; ++c) s = fmaf(f[c*196], aw[oo*32+c], s);
        a[(b*32+oo)*196 + hw] = 1.f/(1.f + __expf(-s));
    }
}

// ---------------------------------------------------------------------------
// patch extraction, m4-interleaved: aP[(b*P+p)*NI + i],
// MpV[((b*P+p)*4 + m4)*NI + i] = float4 of pose rows (coalesced per-lane-i)
// ---------------------------------------------------------------------------
__global__ void k_patch(const float* __restrict__ a_in, const float* __restrict__ M_in,
                        float* __restrict__ aP, float4* __restrict__ MpV,
                        int B, int K, int stride, int h, int w, int oh, int ow) {
    int P = oh*ow, KK = K*K, ni = B*KK;
    int idx = blockIdx.x * blockDim.x + threadIdx.x;
    if (idx >= 16*ni*P) return;
    int i = idx % ni, p = (idx/ni) % P, b = idx/(ni*P);
    int Bi = i / KK, kk = i % KK, ki = kk / K, kj = kk % K;
    int py = p / ow, px = p % ow;
    int src = (py*stride + ki)*w + (px*stride + kj);
    int hw = h*w;
    aP[idx] = a_in[(b*B + Bi)*hw + src];
    const float* Ms = M_in + (size_t)((b*B + Bi)*16)*hw + src;
    size_t base = (size_t)(b*P + p)*4;
    #pragma unroll
    for (int m4 = 0; m4 < 4; ++m4)
        MpV[(base + m4)*ni + i] = make_float4(Ms[(4*m4+0)*hw], Ms[(4*m4+1)*hw],
                                              Ms[(4*m4+2)*hw], Ms[(4*m4+3)*hw]);
}

// W transpose, m4-interleaved: WtV[(c*4+m4)*NI + i] = float4(W[(i*C+c)*16+4*m4..])
__global__ void k_wt(const float* __restrict__ W, float4* __restrict__ WtV,
                     int NI, int C) {
    int idx = blockIdx.x * blockDim.x + threadIdx.x;
    if (idx >= NI*C) return;
    int i = idx % NI, c = idx/NI;
    const float* src = W + (size_t)(i*C + c)*16;
    #pragma unroll
    for (int m4 = 0; m4 < 4; ++m4)
        WtV[((size_t)c*4 + m4)*NI + i] = make_float4(src[4*m4+0], src[4*m4+1],
                                                     src[4*m4+2], src[4*m4+3]);
}

// ---------------------------------------------------------------------------
// EM stats: 4 waves/block, wave w -> c = cg*4+w, shared (b,p) slice.
// LDS-transpose reduction + lane-distributed epilogue.
// Stores PACKED stats: G[16], H2[16], K1 (36-float row).
// ---------------------------------------------------------------------------
template<int NI, int NJ, int P, int C>
__global__ __launch_bounds__(256)
void k_stats(const float* __restrict__ aP, const float4* __restrict__ MpV,
             const float4* __restrict__ WtV, const float* __restrict__ svb,
             const float* __restrict__ mxs, const float* __restrict__ ism,
             const float* __restrict__ beta_a, const float* __restrict__ beta_u,
             float* __restrict__ statP,
             float* __restrict__ a_fin, float* __restrict__ M_fin,
             int t, float lam, int fin)
{
    constexpr int NIT = (NI + 63) / 64;
    constexpr int RS = 68;              // floats per row: 16B-aligned, bank-spread
    __shared__ float sRed[4][33*RS];    // ~36KB
    int wave = threadIdx.x >> 6, lane = threadIdx.x & 63;
    int g  = blockIdx.x % (16*P);
    int cg = blockIdx.x / (16*P);
    int c  = cg*4 + wave;
    int bb = g / P, p = g % P;
    int j  = c*P + p;

    const float*  aPb = aP  + (size_t)(bb*P + p)*NI;
    const float4* Mb  = MpV + (size_t)(bb*P + p)*4*NI;
    const float4* Wb  = WtV + (size_t)c*4*NI;
    const float*  svr = svb + (size_t)(bb*NJ + j)*NI;
    const float*  mxb = mxs + bb*NI;
    const float*  imb = ism + bb*NI;

    float accw = 0.f, accm[16], acc2[16];
    #pragma unroll
    for (int m = 0; m < 16; ++m) { accm[m] = 0.f; acc2[m] = 0.f; }

    for (int it = 0; it < NIT; ++it) {
        int i = lane + it*64;
        if ((NI % 64 == 0) || (i < NI)) {
            float r;
            if (t == 0) r = 1.f / NJ;
            else        r = __expf(svr[i] - mxb[i]) * imb[i];
            float wgt = r * aPb[i];
            float4 m0 = Mb[0*NI + i], m1 = Mb[1*NI + i];
            float4 m2 = Mb[2*NI + i], m3 = Mb[3*NI + i];
            accw += wgt;
            #pragma unroll
            for (int rr = 0; rr < 4; ++rr) {
                float4 w = Wb[rr*NI + i];
                float v0 = fmaf(w.w, m3.x, fmaf(w.z, m2.x, fmaf(w.y, m1.x, w.x*m0.x)));
                float v1 = fmaf(w.w, m3.y, fmaf(w.z, m2.y, fmaf(w.y, m1.y, w.x*m0.y)));
                float v2 = fmaf(w.w, m3.z, fmaf(w.z, m2.z, fmaf(w.y, m1.z, w.x*m0.z)));
                float v3 = fmaf(w.w, m3.w, fmaf(w.z, m2.w, fmaf(w.y, m1.w, w.x*m0.w)));
                float t0 = wgt*v0, t1 = wgt*v1, t2 = wgt*v2, t3 = wgt*v3;
                accm[rr*4+0] += t0; acc2[rr*4+0] = fmaf(t0, v0, acc2[rr*4+0]);
                accm[rr*4+1] += t1; acc2[rr*4+1] = fmaf(t1, v1, acc2[rr*4+1]);
                accm[rr*4+2] += t2; acc2[rr*4+2] = fmaf(t2, v2, acc2[rr*4+2]);
                accm[rr*4+3] += t3; acc2[rr*4+3] = fmaf(t3, v3, acc2[rr*4+3]);
            }
        }
    }

    // LDS transpose: [value][lane] rows; same-wave so no barrier needed
    float* row = sRed[wave];
    row[0*RS + lane] = accw;
    #pragma unroll
    for (int m = 0; m < 16; ++m) {
        row[(1+m)*RS + lane]  = accm[m];
        row[(17+m)*RS + lane] = acc2[m];
    }
    float S = 0.f;
    if (lane < 33) {
        const float4* r4 = (const float4*)(row + lane*RS);
        float4 s4 = make_float4(0.f, 0.f, 0.f, 0.f);
        #pragma unroll
        for (int k = 0; k < 16; ++k) {
            float4 v = r4[k];
            s4.x += v.x; s4.y += v.y; s4.z += v.z; s4.w += v.w;
        }
        S = (s4.x + s4.y) + (s4.z + s4.w);
    }
    float coeff = fmaxf(__shfl(S, 0), 1e-8f);
    float Sn = S / coeff;               // lanes 1..16: mu_m ; lanes 17..32: E[V^2]_m
    bool sig_lane = (lane >= 17 && lane < 33);
    int src = sig_lane ? (lane - 16) : 0;
    float muk = __shfl(Sn, src);        // mu_m on sigma lanes
    float lg = 0.f, iv = 0.f;
    if (sig_lane) {
        float s = fmaxf(Sn - muk*muk, 1e-8f);
        lg = __logf(s);
        iv = 1.f / s;
    }
    float v = sig_lane ? lg : 0.f;
    #pragma unroll
    for (int off = 1; off < 64; off <<= 1) v += __shfl_xor(v, off);
    float lsum = v;
    float ao = 1.f/(1.f + __expf(-(lam * (beta_a[j % C] - (16.f*beta_u[j % C] + 0.5f*lsum) * coeff))));
    float G = 0.f, H2 = 0.f, gmu2 = 0.f;
    if (sig_lane) {
        G = -0.5f*ao*iv;
        H2 = -2.f*G*muk;
        gmu2 = G*muk*muk;
    }
    float u = sig_lane ? gmu2 : 0.f;
    #pragma unroll
    for (int off = 1; off < 64; off <<= 1) u += __shfl_xor(u, off);
    float K1 = fmaf(-0.5f*ao, 16.f*LN2PI + lsum, u);

    float* st = statP + (size_t)(bb*NJ + j)*36;
    if (sig_lane) {
        st[lane-17]      = G;
        st[16 + lane-17] = H2;
    }
    if (lane == 0) st[32] = K1;
    if (fin) {
        if (lane == 0) a_fin[bb*NJ + j] = ao;
        if (lane >= 1 && lane < 17)
            M_fin[(size_t)(bb*16 + lane-1)*NJ + j] = Sn;   // mu, faithful scramble
    }
}

// ---------------------------------------------------------------------------
// k_sv: lane = i, block = 320 thr covers NI<=320, one (b, j-chunk).
// sv = K1 + sum_m V*fma(V,G,H2); online per-lane max/sum; coalesced writes.
// ---------------------------------------------------------------------------
template<int NI, int NJ, int P, int JC>
__global__ __launch_bounds__(320)
void k_sv(const float4* __restrict__ MpV, const float4* __restrict__ WtV,
          const float* __restrict__ statP,
          float* __restrict__ svb, float* __restrict__ pmx, float* __restrict__ psm)
{
    constexpr int NCH = NJ / JC;
    int ch = blockIdx.x % NCH, bb = blockIdx.x / NCH;
    int i = threadIdx.x;
    bool act = (i < NI);
    int j0 = ch * JC;
    int c = j0 / P, p = j0 % P;

    const float4* Mpb = MpV + (size_t)(bb*P)*4*NI;
    float4 w0, w1, w2, w3;
    bool wload = true;
    float mx = -3.0e38f, sm = 0.f;

    for (int jj = 0; jj < JC; ++jj) {
        int j = j0 + jj;
        const float* st = statP + (size_t)(bb*NJ + j)*36;   // uniform -> s_loads
        if (act) {
            if (wload) {
                const float4* Wb = WtV + (size_t)c*4*NI;
                w0 = Wb[0*NI+i]; w1 = Wb[1*NI+i]; w2 = Wb[2*NI+i]; w3 = Wb[3*NI+i];
            }
            const float4* Mb = Mpb + (size_t)p*4*NI;
            float4 m0 = Mb[0*NI+i], m1 = Mb[1*NI+i], m2 = Mb[2*NI+i], m3 = Mb[3*NI+i];
            float V[16];
            {
                float4 w = w0;
                V[0] = fmaf(w.w, m3.x, fmaf(w.z, m2.x, fmaf(w.y, m1.x, w.x*m0.x)));
                V[1] = fmaf(w.w, m3.y, fmaf(w.z, m2.y, fmaf(w.y, m1.y, w.x*m0.y)));
                V[2] = fmaf(w.w, m3.z, fmaf(w.z, m2.z, fmaf(w.y, m1.z, w.x*m0.z)));
                V[3] = fmaf(w.w, m3.w, fmaf(w.z, m2.w, fmaf(w.y, m1.w, w.x*m0.w)));
                w = w1;
                V[4] = fmaf(w.w, m3.x, fmaf(w.z, m2.x, fmaf(w.y, m1.x, w.x*m0.x)));
                V[5] = fmaf(w.w, m3.y, fmaf(w.z, m2.y, fmaf(w.y, m1.y, w.x*m0.y)));
                V[6] = fmaf(w.w, m3.z, fmaf(w.z, m2.z, fmaf(w.y, m1.z, w.x*m0.z)));
                V[7] = fmaf(w.w, m3.w, fmaf(w.z, m2.w, fmaf(w.y, m1.w, w.x*m0.w)));
                w = w2;
                V[8]  = fmaf(w.w, m3.x, fmaf(w.z, m2.x, fmaf(w.y, m1.x, w.x*m0.x)));
                V[9]  = fmaf(w.w, m3.y, fmaf(w.z, m2.y, fmaf(w.y, m1.y, w.x*m0.y)));
                V[10] = fmaf(w.w, m3.z, fmaf(w.z, m2.z, fmaf(w.y, m1.z, w.x*m0.z)));
                V[11] = fmaf(w.w, m3.w, fmaf(w.z, m2.w, fmaf(w.y, m1.w, w.x*m0.w)));
                w = w3;
                V[12] = fmaf(w.w, m3.x, fmaf(w.z, m2.x, fmaf(w.y, m1.x, w.x*m0.x)));
                V[13] = fmaf(w.w, m3.y, fmaf(w.z, m2.y, fmaf(w.y, m1.y, w.x*m0.y)));
                V[14] = fmaf(w.w, m3.z, fmaf(w.z, m2.z, fmaf(w.y, m1.z, w.x*m0.z)));
                V[15] = fmaf(w.w, m3.w, fmaf(w.z, m2.w, fmaf(w.y, m1.w, w.x*m0.w)));
            }
            float acc = 0.f;
            #pragma unroll
            for (int m = 0; m < 16; ++m) {
                float tmp = fmaf(V[m], st[m], st[16+m]);
                acc = fmaf(V[m], tmp, acc);
            }
            float sv = st[32] + acc;
            if (sv > mx) { sm = sm*__expf(mx - sv) + 1.f; mx = sv; }
            else         { sm += __expf(sv - mx); }
            svb[(size_t)(bb*NJ + j)*NI + i] = sv;
        }
        ++p;
        if (p == P) { p = 0; ++c; wload = true; } else wload = false;
    }
    if (act) {
        pmx[(size_t)ch*(16*NI) + bb*NI + i] = mx;
        psm[(size_t)ch*(16*NI) + bb*NI + i] = sm;
    }
}

// ---------------------------------------------------------------------------
// combine chunk partials -> mxs, ism (per (b,i))
// ---------------------------------------------------------------------------
__global__ void k_comb(const float* __restrict__ pmx, const float* __restrict__ psm,
                       float* __restrict__ mxs, float* __restrict__ ism,
                       int nch, int ntot)
{
    int idx = blockIdx.x * blockDim.x + threadIdx.x;
    if (idx >= ntot) return;
    float mx = -3.0e38f, sm = 0.f;
    for (int ch = 0; ch < nch; ++ch) {
        float m2 = pmx[(size_t)ch*ntot + idx];
        float s2 = psm[(size_t)ch*ntot + idx];
        float M = fmaxf(mx, m2);
        sm = sm*__expf(mx - M) + s2*__expf(m2 - M);
        mx = M;
    }
    mxs[idx] = mx;
    ism[idx] = 1.f / sm;
}

// ---------------------------------------------------------------------------
// layer 4 fused (round-6, verified): 512 thr; waves 0-4 own one j each.
// ---------------------------------------------------------------------------
__global__ __launch_bounds__(512)
void k_layer4(const float* __restrict__ a3, const float* __restrict__ M3,
              const float* __restrict__ W4, const float* __restrict__ ba4,
              const float* __restrict__ bu4, float* __restrict__ out)
{
    __shared__ float sMt[16*512];
    __shared__ float sA[512];
    __shared__ float sW[2560];
    __shared__ float sR[2560];
    __shared__ float sStat[5][34];

    int b = blockIdx.x, tid = threadIdx.x;
    int lane = tid & 63, wave = tid >> 6;

    for (int k = tid; k < 8192; k += 512) {
        int i = k & 511, m = k >> 9;
        sMt[k] = M3[b*8192 + (i & ~15)*16 + m*16 + (i & 15)];
    }
    sA[tid] = a3[b*512 + tid];
    for (int k = tid; k < 2560; k += 512) { sW[k] = W4[k]; sR[k] = 0.2f; }
    __syncthreads();

    const float lams[3] = {5.0e-4f, 9.75e-4f, 1.426250e-3f};

    for (int t = 0; t < 3; ++t) {
        if (wave < 5) {
            int j = wave;
            float accw = 0.f, accm[16], acc2[16];
            #pragma unroll
            for (int m = 0; m < 16; ++m) { accm[m] = 0.f; acc2[m] = 0.f; }
            for (int u = 0; u < 8; ++u) {
                int i = u*64 + lane;
                float wgt = sR[i*5 + j] * sA[i];
                float Mm[16];
                #pragma unroll
                for (int m = 0; m < 16; ++m) Mm[m] = sMt[m*512 + i];
                const float* Wm = &sW[((i>>4)*5 + j)*16];
                float V[16];
                #pragma unroll
                for (int r = 0; r < 4; ++r)
                    #pragma unroll
                    for (int cc = 0; cc < 4; ++cc) {
                        float s = Wm[r*4+0]*Mm[0*4+cc];
                        s = fmaf(Wm[r*4+1], Mm[1*4+cc], s);
                        s = fmaf(Wm[r*4+2], Mm[2*4+cc], s);
                        s = fmaf(Wm[r*4+3], Mm[3*4+cc], s);
                        V[r*4+cc] = s;
                    }
                V[0] += (float)((i & 15) >> 2) * 0.25f;
                V[1] += (float)(i & 3) * 0.25f;
                accw += wgt;
                #pragma unroll
                for (int m = 0; m < 16; ++m) {
                    float t1 = wgt * V[m];
                    accm[m] += t1;
                    acc2[m] = fmaf(t1, V[m], acc2[m]);
                }
            }
            for (int off = 1; off < 64; off <<= 1) {
                accw += __shfl_xor(accw, off);
                #pragma unroll
                for (int m = 0; m < 16; ++m) accm[m] += __shfl_xor(accm[m], off);
                #pragma unroll
                for (int m = 0; m < 16; ++m) acc2[m] += __shfl_xor(acc2[m], off);
            }
            float coeff = fmaxf(accw, 1e-8f);
            float lsum = 0.f, mu[16], isv[16];
            #pragma unroll
            for (int m = 0; m < 16; ++m) {
                mu[m] = accm[m] / coeff;
                float s = fmaxf(acc2[m]/coeff - mu[m]*mu[m], 1e-8f);
                lsum += __logf(s);
                isv[m] = 1.f / s;
            }
            float ao = 1.f/(1.f + __expf(-(lams[t] * (ba4[j] - (16.f*bu4[j] + 0.5f*lsum) * coeff))));
            if (lane == 0) {
                #pragma unroll
                for (int m = 0; m < 16; ++m) { sStat[j][m] = mu[m]; sStat[j][16+m] = isv[m]; }
                sStat[j][32] = lsum; sStat[j][33] = ao;
            }
        }
        __syncthreads();
        if (t < 2) {
            int i = tid;
            float Mm[16];
            #pragma unroll
            for (int m = 0; m < 16; ++m) Mm[m] = sMt[m*512 + i];
            float sv[5], mxv = -3.0e38f;
            #pragma unroll
            for (int j = 0; j < 5; ++j) {
                const float* Wm = &sW[((i>>4)*5 + j)*16];
                float V[16];
                #pragma unroll
                for (int r = 0; r < 4; ++r)
                    #pragma unroll
                    for (int cc = 0; cc < 4; ++cc) {
                        float s = Wm[r*4+0]*Mm[0*4+cc];
                        s = fmaf(Wm[r*4+1], Mm[1*4+cc], s);
                        s = fmaf(Wm[r*4+2], Mm[2*4+cc], s);
                        s = fmaf(Wm[r*4+3], Mm[3*4+cc], s);
                        V[r*4+cc] = s;
                    }
                V[0] += (float)((i & 15) >> 2) * 0.25f;
                V[1] += (float)(i & 3) * 0.25f;
                float q = 0.f;
                #pragma unroll
                for (int m = 0; m < 16; ++m) {
                    float d = V[m] - sStat[j][m];
                    q = fmaf(d*d, sStat[j][16+m], q);
                }
                float logp = -0.5f * (16.f*LN2PI + sStat[j][32] + q);
                sv[j] = sStat[j][33] * logp;
                mxv = fmaxf(mxv, sv[j]);
            }
            float sum = 0.f;
            #pragma unroll
            for (int j = 0; j < 5; ++j) { sv[j] = __expf(sv[j] - mxv); sum += sv[j]; }
            float inv = 1.f / sum;
            #pragma unroll
            for (int j = 0; j < 5; ++j) sR[i*5 + j] = sv[j] * inv;
            __syncthreads();
        }
    }
    if (tid < 5) out[b*5 + tid] = sStat[tid][33];
}

// ---------------------------------------------------------------------------
// host: one EM layer (layers 2/3)
// ---------------------------------------------------------------------------
template<int NI, int NJ, int P, int C, int JC>
static void run_em(hipStream_t stream,
                   const float* aP, const float4* MpV, const float4* WtV,
                   const float* ba, const float* bu,
                   float* statP, float* svb, float* mxs, float* ism,
                   float* pmx, float* psm,
                   float* a_fin, float* M_fin)
{
    constexpr int NCH = NJ / JC;
    const float lams[3] = {5.0e-4f, 9.75e-4f, 1.426250e-3f};
    for (int t = 0; t < 3; ++t) {
        k_stats<NI,NJ,P,C><<<16*NJ/4, 256, 0, stream>>>(
            aP, MpV, WtV, svb, mxs, ism, ba, bu, statP, a_fin, M_fin,
            t, lams[t], (t == 2) ? 1 : 0);
        if (t < 2) {
            k_sv<NI,NJ,P,JC><<<16*NCH, 320, 0, stream>>>(MpV, WtV, statP, svb, pmx, psm);
            k_comb<<<(16*NI + 255)/256, 256, 0, stream>>>(pmx, psm, mxs, ism, NCH, 16*NI);
        }
    }
}

extern "C" void kernel_launch(void* const* d_in, const int* in_sizes, int n_in,
                              void* d_out, int out_size, void* d_ws, size_t ws_size,
                              hipStream_t stream) {
    (void)in_sizes; (void)n_in; (void)out_size; (void)ws_size;
    const float* x       = (const float*)d_in[0];
    const float* conv_w  = (const float*)d_in[1];
    const float* conv_b  = (const float*)d_in[2];
    const float* pose_w  = (const float*)d_in[3];
    const float* pose_b  = (const float*)d_in[4];
    const float* act_w   = (const float*)d_in[5];
    const float* act_b   = (const float*)d_in[6];
    const float* W2      = (const float*)d_in[7];
    const float* beta_a2 = (const float*)d_in[8];
    const float* beta_u2 = (const float*)d_in[9];
    const float* W3      = (const float*)d_in[10];
    const float* beta_a3 = (const float*)d_in[11];
    const float* beta_u3 = (const float*)d_in[12];
    const float* W4      = (const float*)d_in[13];
    const float* beta_a4 = (const float*)d_in[14];
    const float* beta_u4 = (const float*)d_in[15];

    // workspace layout (floats), ~46.2 MB total
    float* ws    = (float*)d_ws;
    float* fea   = ws;                    // 100352
    float* a1    = fea   + 100352;        // 100352
    float* M1    = a1    + 100352;        // 1605632
    float* aP    = M1    + 1605632;       // 165888 (max)
    float* Mp    = aP    + 165888;        // 2654208 (max, float4-aligned: offset mult of 4)
    float* Wt    = Mp    + 2654208;       // 147456
    float* statP = Wt    + 147456;        // 663552 (16*1152*36)
    float* svb   = statP + 663552;        // 5308416 (16*1152*288)
    float* mxs   = svb   + 5308416;       // 4608
    float* ismb  = mxs   + 4608;          // 4608
    float* pmx   = ismb  + 4608;          // 165888
    float* psm   = pmx   + 165888;        // 165888
    float* a2    = psm   + 165888;        // 18432
    float* M2    = a2    + 18432;         // 294912
    float* a3    = M2    + 294912;        // 8192
    float* M3    = a3    + 8192;          // 131072

    float4* MpV = (float4*)Mp;
    float4* WtV = (float4*)Wt;

    // stem + primary caps
    k_stem<<<(16*32*196 + 255)/256, 256, 0, stream>>>(x, conv_w, conv_b, fea);
    k_primary<<<(16*544*196 + 255)/256, 256, 0, stream>>>(fea, pose_w, pose_b,
                                                          act_w, act_b, M1, a1);

    // layer 2: NI=288, NJ=1152, P=36, C=32, JC=32
    k_patch<<<(16*288*36 + 255)/256, 256, 0, stream>>>(a1, M1, aP, MpV, 32, 3, 2, 14, 14, 6, 6);
    k_wt<<<(288*32 + 255)/256, 256, 0, stream>>>(W2, WtV, 288, 32);
    run_em<288,1152,36,32,32>(stream, aP, MpV, WtV, beta_a2, beta_u2,
                              statP, svb, mxs, ismb, pmx, psm, a2, M2);

    // layer 3: NI=288, NJ=512, P=16, C=32, JC=16
    k_patch<<<(16*288*16 + 255)/256, 256, 0, stream>>>(a2, M2, aP, MpV, 32, 3, 1, 6, 6, 4, 4);
    k_wt<<<(288*32 + 255)/256, 256, 0, stream>>>(W3, WtV, 288, 32);
    run_em<288,512,16,32,16>(stream, aP, MpV, WtV, beta_a3, beta_u3,
                             statP, svb, mxs, ismb, pmx, psm, a3, M3);

    // layer 4 fused
    k_layer4<<<16, 512, 0, stream>>>(a3, M3, W4, beta_a4, beta_u4, (float*)d_out);
}

// Round 9
// 475.096 us; speedup vs baseline: 6.1945x; 1.0313x over previous
//
#include <hip/hip_runtime.h>
#include <math.h>

#define LN2PI 1.83787706640934548356f

// ---------------------------------------------------------------------------
// stem: conv 5x5 stride 2 valid + bias + relu : (16,2,32,32) -> (16,32,14,14)
// ---------------------------------------------------------------------------
__global__ void k_stem(const float* __restrict__ x, const float* __restrict__ w,
                       const float* __restrict__ bias, float* __restrict__ fea) {
    int idx = blockIdx.x * blockDim.x + threadIdx.x;
    if (idx >= 16*32*14*14) return;
    int ox = idx % 14, oy = (idx/14) % 14, oc = (idx/196) % 32, b = idx/(196*32);
    float s = bias[oc];
    const float* xb = x + b*2*1024;
    const float* wc = w + oc*2*25;
    #pragma unroll
    for (int ic = 0; ic < 2; ++ic)
        #pragma unroll
        for (int ky = 0; ky < 5; ++ky)
            #pragma unroll
            for (int kx = 0; kx < 5; ++kx)
                s = fmaf(xb[ic*1024 + (oy*2+ky)*32 + (ox*2+kx)],
                         wc[ic*25 + ky*5 + kx], s);
    fea[idx] = fmaxf(s, 0.f);
}

// ---------------------------------------------------------------------------
// primary caps
// ---------------------------------------------------------------------------
__global__ void k_primary(const float* __restrict__ fea,
                          const float* __restrict__ pw, const float* __restrict__ pb,
                          const float* __restrict__ aw, const float* __restrict__ ab,
                          float* __restrict__ M, float* __restrict__ a) {
    int idx = blockIdx.x * blockDim.x + threadIdx.x;
    if (idx >= 16*544*196) return;
    int hw = idx % 196, o = (idx/196) % 544, b = idx/(196*544);
    const float* f = fea + b*32*196 + hw;
    if (o < 512) {
        float s = pb[o];
        #pragma unroll
        for (int c = 0; c < 32; ++c) s = fmaf(f[c*196], pw[o*32+c], s);
        M[(b*512+o)*196 + hw] = s;
    } else {
        int oo = o - 512;
        float s = ab[oo];
        #pragma unroll
        for (int c = 0; c < 32; ++c) s = fmaf(f[c*196], aw[oo*32+c], s);
        a[(b*32+oo)*196 + hw] = 1.f/(1.f + __expf(-s));
    }
}

// ---------------------------------------------------------------------------
// patch extraction, m4-interleaved: aP[(b*P+p)*NI + i],
// MpV[((b*P+p)*4 + m4)*NI + i] = float4 of pose rows (coalesced per-lane-i)
// ---------------------------------------------------------------------------
__global__ void k_patch(const float* __restrict__ a_in, const float* __restrict__ M_in,
                        float* __restrict__ aP, float4* __restrict__ MpV,
                        int B, int K, int stride, int h, int w, int oh, int ow) {
    int P = oh*ow, KK = K*K, ni = B*KK;
    int idx = blockIdx.x * blockDim.x + threadIdx.x;
    if (idx >= 16*ni*P) return;
    int i = idx % ni, p = (idx/ni) % P, b = idx/(ni*P);
    int Bi = i / KK, kk = i % KK, ki = kk / K, kj = kk % K;
    int py = p / ow, px = p % ow;
    int src = (py*stride + ki)*w + (px*stride + kj);
    int hw = h*w;
    aP[idx] = a_in[(b*B + Bi)*hw + src];
    const float* Ms = M_in + (size_t)((b*B + Bi)*16)*hw + src;
    size_t base = (size_t)(b*P + p)*4;
    #pragma unroll
    for (int m4 = 0; m4 < 4; ++m4)
        MpV[(base + m4)*ni + i] = make_float4(Ms[(4*m4+0)*hw], Ms[(4*m4+1)*hw],
                                              Ms[(4*m4+2)*hw], Ms[(4*m4+3)*hw]);
}

// W transpose, m4-interleaved: WtV[(c*4+m4)*NI + i] = float4(W[(i*C+c)*16+4*m4..])
__global__ void k_wt(const float* __restrict__ W, float4* __restrict__ WtV,
                     int NI, int C) {
    int idx = blockIdx.x * blockDim.x + threadIdx.x;
    if (idx >= NI*C) return;
    int i = idx % NI, c = idx/NI;
    const float* src = W + (size_t)(i*C + c)*16;
    #pragma unroll
    for (int m4 = 0; m4 < 4; ++m4)
        WtV[((size_t)c*4 + m4)*NI + i] = make_float4(src[4*m4+0], src[4*m4+1],
                                                     src[4*m4+2], src[4*m4+3]);
}

// ---------------------------------------------------------------------------
// EM stats: 4 waves/block, wave w -> c = cg*4+w, shared (b,p) slice.
// LDS-transpose reduction + lane-distributed epilogue.
// Stores PACKED stats: G[16], H2[16], K1 (36-float row).
// ---------------------------------------------------------------------------
template<int NI, int NJ, int P, int C>
__global__ __launch_bounds__(256)
void k_stats(const float* __restrict__ aP, const float4* __restrict__ MpV,
             const float4* __restrict__ WtV, const float* __restrict__ svb,
             const float* __restrict__ mxs, const float* __restrict__ ism,
             const float* __restrict__ beta_a, const float* __restrict__ beta_u,
             float* __restrict__ statP,
             float* __restrict__ a_fin, float* __restrict__ M_fin,
             int t, float lam, int fin)
{
    constexpr int NIT = (NI + 63) / 64;
    constexpr int RS = 68;              // floats per row: 16B-aligned, bank-spread
    __shared__ float sRed[4][33*RS];    // ~36KB
    int wave = threadIdx.x >> 6, lane = threadIdx.x & 63;
    int g  = blockIdx.x % (16*P);
    int cg = blockIdx.x / (16*P);
    int c  = cg*4 + wave;
    int bb = g / P, p = g % P;
    int j  = c*P + p;

    const float*  aPb = aP  + (size_t)(bb*P + p)*NI;
    const float4* Mb  = MpV + (size_t)(bb*P + p)*4*NI;
    const float4* Wb  = WtV + (size_t)c*4*NI;
    const float*  svr = svb + (size_t)(bb*NJ + j)*NI;
    const float*  mxb = mxs + bb*NI;
    const float*  imb = ism + bb*NI;

    float accw = 0.f, accm[16], acc2[16];
    #pragma unroll
    for (int m = 0; m < 16; ++m) { accm[m] = 0.f; acc2[m] = 0.f; }

    for (int it = 0; it < NIT; ++it) {
        int i = lane + it*64;
        if ((NI % 64 == 0) || (i < NI)) {
            float r;
            if (t == 0) r = 1.f / NJ;
            else        r = __expf(svr[i] - mxb[i]) * imb[i];
            float wgt = r * aPb[i];
            float4 m0 = Mb[0*NI + i], m1 = Mb[1*NI + i];
            float4 m2 = Mb[2*NI + i], m3 = Mb[3*NI + i];
            accw += wgt;
            #pragma unroll
            for (int rr = 0; rr < 4; ++rr) {
                float4 w = Wb[rr*NI + i];
                float v0 = fmaf(w.w, m3.x, fmaf(w.z, m2.x, fmaf(w.y, m1.x, w.x*m0.x)));
                float v1 = fmaf(w.w, m3.y, fmaf(w.z, m2.y, fmaf(w.y, m1.y, w.x*m0.y)));
                float v2 = fmaf(w.w, m3.z, fmaf(w.z, m2.z, fmaf(w.y, m1.z, w.x*m0.z)));
                float v3 = fmaf(w.w, m3.w, fmaf(w.z, m2.w, fmaf(w.y, m1.w, w.x*m0.w)));
                float t0 = wgt*v0, t1 = wgt*v1, t2 = wgt*v2, t3 = wgt*v3;
                accm[rr*4+0] += t0; acc2[rr*4+0] = fmaf(t0, v0, acc2[rr*4+0]);
                accm[rr*4+1] += t1; acc2[rr*4+1] = fmaf(t1, v1, acc2[rr*4+1]);
                accm[rr*4+2] += t2; acc2[rr*4+2] = fmaf(t2, v2, acc2[rr*4+2]);
                accm[rr*4+3] += t3; acc2[rr*4+3] = fmaf(t3, v3, acc2[rr*4+3]);
            }
        }
    }

    // LDS transpose: [value][lane] rows; same-wave so no barrier needed
    float* row = sRed[wave];
    row[0*RS + lane] = accw;
    #pragma unroll
    for (int m = 0; m < 16; ++m) {
        row[(1+m)*RS + lane]  = accm[m];
        row[(17+m)*RS + lane] = acc2[m];
    }
    float S = 0.f;
    if (lane < 33) {
        const float4* r4 = (const float4*)(row + lane*RS);
        float4 s4 = make_float4(0.f, 0.f, 0.f, 0.f);
        #pragma unroll
        for (int k = 0; k < 16; ++k) {
            float4 v = r4[k];
            s4.x += v.x; s4.y += v.y; s4.z += v.z; s4.w += v.w;
        }
        S = (s4.x + s4.y) + (s4.z + s4.w);
    }
    float coeff = fmaxf(__shfl(S, 0), 1e-8f);
    float Sn = S / coeff;               // lanes 1..16: mu_m ; lanes 17..32: E[V^2]_m
    bool sig_lane = (lane >= 17 && lane < 33);
    int src = sig_lane ? (lane - 16) : 0;
    float muk = __shfl(Sn, src);        // mu_m on sigma lanes
    float lg = 0.f, iv = 0.f;
    if (sig_lane) {
        float s = fmaxf(Sn - muk*muk, 1e-8f);
        lg = __logf(s);
        iv = 1.f / s;
    }
    float v = sig_lane ? lg : 0.f;
    #pragma unroll
    for (int off = 1; off < 64; off <<= 1) v += __shfl_xor(v, off);
    float lsum = v;
    float ao = 1.f/(1.f + __expf(-(lam * (beta_a[j % C] - (16.f*beta_u[j % C] + 0.5f*lsum) * coeff))));
    float G = 0.f, H2 = 0.f, gmu2 = 0.f;
    if (sig_lane) {
        G = -0.5f*ao*iv;
        H2 = -2.f*G*muk;
        gmu2 = G*muk*muk;
    }
    float u = sig_lane ? gmu2 : 0.f;
    #pragma unroll
    for (int off = 1; off < 64; off <<= 1) u += __shfl_xor(u, off);
    float K1 = fmaf(-0.5f*ao, 16.f*LN2PI + lsum, u);

    float* st = statP + (size_t)(bb*NJ + j)*36;
    if (sig_lane) {
        st[lane-17]      = G;
        st[16 + lane-17] = H2;
    }
    if (lane == 0) st[32] = K1;
    if (fin) {
        if (lane == 0) a_fin[bb*NJ + j] = ao;
        if (lane >= 1 && lane < 17)
            M_fin[(size_t)(bb*16 + lane-1)*NJ + j] = Sn;   // mu, faithful scramble
    }
}

// ---------------------------------------------------------------------------
// k_sv: block = (b,p), lane = i. M fragment register-resident (loaded ONCE);
// loop over all c: load W[c][i] (L2-resident, shared by all blocks/batches),
// compute sv, online per-lane max/sum, coalesced svb writes. Partials per p.
// ---------------------------------------------------------------------------
template<int NI, int NJ, int P, int C>
__global__ __launch_bounds__(320)
void k_sv(const float4* __restrict__ MpV, const float4* __restrict__ WtV,
          const float* __restrict__ statP,
          float* __restrict__ svb, float* __restrict__ pmx, float* __restrict__ psm)
{
    int p = blockIdx.x % P, bb = blockIdx.x / P;
    int i = threadIdx.x;
    bool act = (i < NI);

    float4 m0, m1, m2, m3;
    if (act) {
        const float4* Mb = MpV + (size_t)(bb*P + p)*4*NI;
        m0 = Mb[0*NI+i]; m1 = Mb[1*NI+i]; m2 = Mb[2*NI+i]; m3 = Mb[3*NI+i];
    }
    float mx = -3.0e38f, sm = 0.f;

    for (int c = 0; c < C; ++c) {
        int j = c*P + p;
        const float* st = statP + (size_t)(bb*NJ + j)*36;   // uniform -> s_loads
        if (act) {
            const float4* Wb = WtV + (size_t)c*4*NI;
            float4 w0 = Wb[0*NI+i], w1 = Wb[1*NI+i], w2 = Wb[2*NI+i], w3 = Wb[3*NI+i];
            float V[16];
            {
                float4 w = w0;
                V[0] = fmaf(w.w, m3.x, fmaf(w.z, m2.x, fmaf(w.y, m1.x, w.x*m0.x)));
                V[1] = fmaf(w.w, m3.y, fmaf(w.z, m2.y, fmaf(w.y, m1.y, w.x*m0.y)));
                V[2] = fmaf(w.w, m3.z, fmaf(w.z, m2.z, fmaf(w.y, m1.z, w.x*m0.z)));
                V[3] = fmaf(w.w, m3.w, fmaf(w.z, m2.w, fmaf(w.y, m1.w, w.x*m0.w)));
                w = w1;
                V[4] = fmaf(w.w, m3.x, fmaf(w.z, m2.x, fmaf(w.y, m1.x, w.x*m0.x)));
                V[5] = fmaf(w.w, m3.y, fmaf(w.z, m2.y, fmaf(w.y, m1.y, w.x*m0.y)));
                V[6] = fmaf(w.w, m3.z, fmaf(w.z, m2.z, fmaf(w.y, m1.z, w.x*m0.z)));
                V[7] = fmaf(w.w, m3.w, fmaf(w.z, m2.w, fmaf(w.y, m1.w, w.x*m0.w)));
                w = w2;
                V[8]  = fmaf(w.w, m3.x, fmaf(w.z, m2.x, fmaf(w.y, m1.x, w.x*m0.x)));
                V[9]  = fmaf(w.w, m3.y, fmaf(w.z, m2.y, fmaf(w.y, m1.y, w.x*m0.y)));
                V[10] = fmaf(w.w, m3.z, fmaf(w.z, m2.z, fmaf(w.y, m1.z, w.x*m0.z)));
                V[11] = fmaf(w.w, m3.w, fmaf(w.z, m2.w, fmaf(w.y, m1.w, w.x*m0.w)));
                w = w3;
                V[12] = fmaf(w.w, m3.x, fmaf(w.z, m2.x, fmaf(w.y, m1.x, w.x*m0.x)));
                V[13] = fmaf(w.w, m3.y, fmaf(w.z, m2.y, fmaf(w.y, m1.y, w.x*m0.y)));
                V[14] = fmaf(w.w, m3.z, fmaf(w.z, m2.z, fmaf(w.y, m1.z, w.x*m0.z)));
                V[15] = fmaf(w.w, m3.w, fmaf(w.z, m2.w, fmaf(w.y, m1.w, w.x*m0.w)));
            }
            float acc = 0.f;
            #pragma unroll
            for (int m = 0; m < 16; ++m) {
                float tmp = fmaf(V[m], st[m], st[16+m]);
                acc = fmaf(V[m], tmp, acc);
            }
            float sv = st[32] + acc;
            if (sv > mx) { sm = sm*__expf(mx - sv) + 1.f; mx = sv; }
            else         { sm += __expf(sv - mx); }
            svb[(size_t)(bb*NJ + j)*NI + i] = sv;
        }
    }
    if (act) {
        pmx[(size_t)p*(16*NI) + bb*NI + i] = mx;
        psm[(size_t)p*(16*NI) + bb*NI + i] = sm;
    }
}

// ---------------------------------------------------------------------------
// combine chunk partials -> mxs, ism (per (b,i))
// ---------------------------------------------------------------------------
__global__ void k_comb(const float* __restrict__ pmx, const float* __restrict__ psm,
                       float* __restrict__ mxs, float* __restrict__ ism,
                       int nch, int ntot)
{
    int idx = blockIdx.x * blockDim.x + threadIdx.x;
    if (idx >= ntot) return;
    float mx = -3.0e38f, sm = 0.f;
    for (int ch = 0; ch < nch; ++ch) {
        float m2 = pmx[(size_t)ch*ntot + idx];
        float s2 = psm[(size_t)ch*ntot + idx];
        float M = fmaxf(mx, m2);
        sm = sm*__expf(mx - M) + s2*__expf(m2 - M);
        mx = M;
    }
    mxs[idx] = mx;
    ism[idx] = 1.f / sm;
}

// ---------------------------------------------------------------------------
// layer 4 fused (verified): 512 thr; waves 0-4 own one j each.
// ---------------------------------------------------------------------------
__global__ __launch_bounds__(512)
void k_layer4(const float* __restrict__ a3, const float* __restrict__ M3,
              const float* __restrict__ W4, const float* __restrict__ ba4,
              const float* __restrict__ bu4, float* __restrict__ out)
{
    __shared__ float sMt[16*512];
    __shared__ float sA[512];
    __shared__ float sW[2560];
    __shared__ float sR[2560];
    __shared__ float sStat[5][34];

    int b = blockIdx.x, tid = threadIdx.x;
    int lane = tid & 63, wave = tid >> 6;

    for (int k = tid; k < 8192; k += 512) {
        int i = k & 511, m = k >> 9;
        sMt[k] = M3[b*8192 + (i & ~15)*16 + m*16 + (i & 15)];
    }
    sA[tid] = a3[b*512 + tid];
    for (int k = tid; k < 2560; k += 512) { sW[k] = W4[k]; sR[k] = 0.2f; }
    __syncthreads();

    const float lams[3] = {5.0e-4f, 9.75e-4f, 1.426250e-3f};

    for (int t = 0; t < 3; ++t) {
        if (wave < 5) {
            int j = wave;
            float accw = 0.f, accm[16], acc2[16];
            #pragma unroll
            for (int m = 0; m < 16; ++m) { accm[m] = 0.f; acc2[m] = 0.f; }
            for (int u = 0; u < 8; ++u) {
                int i = u*64 + lane;
                float wgt = sR[i*5 + j] * sA[i];
                float Mm[16];
                #pragma unroll
                for (int m = 0; m < 16; ++m) Mm[m] = sMt[m*512 + i];
                const float* Wm = &sW[((i>>4)*5 + j)*16];
                float V[16];
                #pragma unroll
                for (int r = 0; r < 4; ++r)
                    #pragma unroll
                    for (int cc = 0; cc < 4; ++cc) {
                        float s = Wm[r*4+0]*Mm[0*4+cc];
                        s = fmaf(Wm[r*4+1], Mm[1*4+cc], s);
                        s = fmaf(Wm[r*4+2], Mm[2*4+cc], s);
                        s = fmaf(Wm[r*4+3], Mm[3*4+cc], s);
                        V[r*4+cc] = s;
                    }
                V[0] += (float)((i & 15) >> 2) * 0.25f;
                V[1] += (float)(i & 3) * 0.25f;
                accw += wgt;
                #pragma unroll
                for (int m = 0; m < 16; ++m) {
                    float t1 = wgt * V[m];
                    accm[m] += t1;
                    acc2[m] = fmaf(t1, V[m], acc2[m]);
                }
            }
            for (int off = 1; off < 64; off <<= 1) {
                accw += __shfl_xor(accw, off);
                #pragma unroll
                for (int m = 0; m < 16; ++m) accm[m] += __shfl_xor(accm[m], off);
                #pragma unroll
                for (int m = 0; m < 16; ++m) acc2[m] += __shfl_xor(acc2[m], off);
            }
            float coeff = fmaxf(accw, 1e-8f);
            float lsum = 0.f, mu[16], isv[16];
            #pragma unroll
            for (int m = 0; m < 16; ++m) {
                mu[m] = accm[m] / coeff;
                float s = fmaxf(acc2[m]/coeff - mu[m]*mu[m], 1e-8f);
                lsum += __logf(s);
                isv[m] = 1.f / s;
            }
            float ao = 1.f/(1.f + __expf(-(lams[t] * (ba4[j] - (16.f*bu4[j] + 0.5f*lsum) * coeff))));
            if (lane == 0) {
                #pragma unroll
                for (int m = 0; m < 16; ++m) { sStat[j][m] = mu[m]; sStat[j][16+m] = isv[m]; }
                sStat[j][32] = lsum; sStat[j][33] = ao;
            }
        }
        __syncthreads();
        if (t < 2) {
            int i = tid;
            float Mm[16];
            #pragma unroll
            for (int m = 0; m < 16; ++m) Mm[m] = sMt[m*512 + i];
            float sv[5], mxv = -3.0e38f;
            #pragma unroll
            for (int j = 0; j < 5; ++j) {
                const float* Wm = &sW[((i>>4)*5 + j)*16];
                float V[16];
                #pragma unroll
                for (int r = 0; r < 4; ++r)
                    #pragma unroll
                    for (int cc = 0; cc < 4; ++cc) {
                        float s = Wm[r*4+0]*Mm[0*4+cc];
                        s = fmaf(Wm[r*4+1], Mm[1*4+cc], s);
                        s = fmaf(Wm[r*4+2], Mm[2*4+cc], s);
                        s = fmaf(Wm[r*4+3], Mm[3*4+cc], s);
                        V[r*4+cc] = s;
                    }
                V[0] += (float)((i & 15) >> 2) * 0.25f;
                V[1] += (float)(i & 3) * 0.25f;
                float q = 0.f;
                #pragma unroll
                for (int m = 0; m < 16; ++m) {
                    float d = V[m] - sStat[j][m];
                    q = fmaf(d*d, sStat[j][16+m], q);
                }
                float logp = -0.5f * (16.f*LN2PI + sStat[j][32] + q);
                sv[j] = sStat[j][33] * logp;
                mxv = fmaxf(mxv, sv[j]);
            }
            float sum = 0.f;
            #pragma unroll
            for (int j = 0; j < 5; ++j) { sv[j] = __expf(sv[j] - mxv); sum += sv[j]; }
            float inv = 1.f / sum;
            #pragma unroll
            for (int j = 0; j < 5; ++j) sR[i*5 + j] = sv[j] * inv;
            __syncthreads();
        }
    }
    if (tid < 5) out[b*5 + tid] = sStat[tid][33];
}

// ---------------------------------------------------------------------------
// host: one EM layer (layers 2/3)
// ---------------------------------------------------------------------------
template<int NI, int NJ, int P, int C>
static void run_em(hipStream_t stream,
                   const float* aP, const float4* MpV, const float4* WtV,
                   const float* ba, const float* bu,
                   float* statP, float* svb, float* mxs, float* ism,
                   float* pmx, float* psm,
                   float* a_fin, float* M_fin)
{
    const float lams[3] = {5.0e-4f, 9.75e-4f, 1.426250e-3f};
    for (int t = 0; t < 3; ++t) {
        k_stats<NI,NJ,P,C><<<16*NJ/4, 256, 0, stream>>>(
            aP, MpV, WtV, svb, mxs, ism, ba, bu, statP, a_fin, M_fin,
            t, lams[t], (t == 2) ? 1 : 0);
        if (t < 2) {
            k_sv<NI,NJ,P,C><<<16*P, 320, 0, stream>>>(MpV, WtV, statP, svb, pmx, psm);
            k_comb<<<(16*NI + 255)/256, 256, 0, stream>>>(pmx, psm, mxs, ism, P, 16*NI);
        }
    }
}

extern "C" void kernel_launch(void* const* d_in, const int* in_sizes, int n_in,
                              void* d_out, int out_size, void* d_ws, size_t ws_size,
                              hipStream_t stream) {
    (void)in_sizes; (void)n_in; (void)out_size; (void)ws_size;
    const float* x       = (const float*)d_in[0];
    const float* conv_w  = (const float*)d_in[1];
    const float* conv_b  = (const float*)d_in[2];
    const float* pose_w  = (const float*)d_in[3];
    const float* pose_b  = (const float*)d_in[4];
    const float* act_w   = (const float*)d_in[5];
    const float* act_b   = (const float*)d_in[6];
    const float* W2      = (const float*)d_in[7];
    const float* beta_a2 = (const float*)d_in[8];
    const float* beta_u2 = (const float*)d_in[9];
    const float* W3      = (const float*)d_in[10];
    const float* beta_a3 = (const float*)d_in[11];
    const float* beta_u3 = (const float*)d_in[12];
    const float* W4      = (const float*)d_in[13];
    const float* beta_a4 = (const float*)d_in[14];
    const float* beta_u4 = (const float*)d_in[15];

    // workspace layout (floats), ~46.2 MB total
    float* ws    = (float*)d_ws;
    float* fea   = ws;                    // 100352
    float* a1    = fea   + 100352;        // 100352
    float* M1    = a1    + 100352;        // 1605632
    float* aP    = M1    + 1605632;       // 165888 (max)
    float* Mp    = aP    + 165888;        // 2654208 (max, float4-aligned)
    float* Wt    = Mp    + 2654208;       // 147456
    float* statP = Wt    + 147456;        // 663552 (16*1152*36)
    float* svb   = statP + 663552;        // 5308416 (16*1152*288)
    float* mxs   = svb   + 5308416;       // 4608
    float* ismb  = mxs   + 4608;          // 4608
    float* pmx   = ismb  + 4608;          // 165888
    float* psm   = pmx   + 165888;        // 165888
    float* a2    = psm   + 165888;        // 18432
    float* M2    = a2    + 18432;         // 294912
    float* a3    = M2    + 294912;        // 8192
    float* M3    = a3    + 8192;          // 131072

    float4* MpV = (float4*)Mp;
    float4* WtV = (float4*)Wt;

    // stem + primary caps
    k_stem<<<(16*32*196 + 255)/256, 256, 0, stream>>>(x, conv_w, conv_b, fea);
    k_primary<<<(16*544*196 + 255)/256, 256, 0, stream>>>(fea, pose_w, pose_b,
                                                          act_w, act_b, M1, a1);

    // layer 2: NI=288, NJ=1152, P=36, C=32
    k_patch<<<(16*288*36 + 255)/256, 256, 0, stream>>>(a1, M1, aP, MpV, 32, 3, 2, 14, 14, 6, 6);
    k_wt<<<(288*32 + 255)/256, 256, 0, stream>>>(W2, WtV, 288, 32);
    run_em<288,1152,36,32>(stream, aP, MpV, WtV, beta_a2, beta_u2,
                           statP, svb, mxs, ismb, pmx, psm, a2, M2);

    // layer 3: NI=288, NJ=512, P=16, C=32
    k_patch<<<(16*288*16 + 255)/256, 256, 0, stream>>>(a2, M2, aP, MpV, 32, 3, 1, 6, 6, 4, 4);
    k_wt<<<(288*32 + 255)/256, 256, 0, stream>>>(W3, WtV, 288, 32);
    run_em<288,512,16,32>(stream, aP, MpV, WtV, beta_a3, beta_u3,
                          statP, svb, mxs, ismb, pmx, psm, a3, M3);

    // layer 4 fused
    k_layer4<<<16, 512, 0, stream>>>(a3, M3, W4, beta_a4, beta_u4, (float*)d_out);
}